// Round 1
// baseline (2979.875 us; speedup 1.0000x reference)
//
#include <hip/hip_runtime.h>
#include <math.h>

#define N_NODES 100000
#define E_TOT   1700000
#define C1      512
#define NB_SCAN 98   // ceil(100000/1024)

static inline int cdiv(int a, int b){ return (a + b - 1) / b; }

// ---------- ordered-float encoding for atomic max ----------
__device__ __forceinline__ unsigned fenc(float f){
  unsigned u = __float_as_uint(f);
  return (u >> 31) ? ~u : (u | 0x80000000u);
}
__device__ __forceinline__ float fdec(unsigned e){
  return (e & 0x80000000u) ? __uint_as_float(e ^ 0x80000000u) : __uint_as_float(~e);
}
// note: fdec(0) = NaN  -> "empty segment" -> replaced by 0 like the reference

// ---------- utility ----------
__global__ void zero_kernel(int* __restrict__ p, int n){
  int i = blockIdx.x * 256 + threadIdx.x;
  if (i < n) p[i] = 0;
}

// ---------- CSR build (dst-indexed), reused by all 5 fine layers ----------
__global__ void count_deg(const int* __restrict__ dst, int* __restrict__ deg){
  int e = blockIdx.x * 256 + threadIdx.x;
  if (e < E_TOT) atomicAdd(&deg[dst[e]], 1);
}

__global__ void scan1(const int* __restrict__ deg, int* __restrict__ row_start,
                      int* __restrict__ partials){
  __shared__ int sm[256];
  int t = threadIdx.x, b = blockIdx.x;
  int base = b * 1024 + t * 4;
  int d0 = (base + 0 < N_NODES) ? deg[base + 0] : 0;
  int d1 = (base + 1 < N_NODES) ? deg[base + 1] : 0;
  int d2 = (base + 2 < N_NODES) ? deg[base + 2] : 0;
  int d3 = (base + 3 < N_NODES) ? deg[base + 3] : 0;
  int s = d0 + d1 + d2 + d3;
  sm[t] = s; __syncthreads();
  for (int off = 1; off < 256; off <<= 1){
    int v = (t >= off) ? sm[t - off] : 0;
    __syncthreads();
    sm[t] += v;
    __syncthreads();
  }
  int excl = sm[t] - s;
  if (base + 0 < N_NODES) row_start[base + 0] = excl;
  if (base + 1 < N_NODES) row_start[base + 1] = excl + d0;
  if (base + 2 < N_NODES) row_start[base + 2] = excl + d0 + d1;
  if (base + 3 < N_NODES) row_start[base + 3] = excl + d0 + d1 + d2;
  if (t == 255) partials[b] = sm[255];
}

__global__ void scan2(int* __restrict__ partials){
  if (threadIdx.x == 0 && blockIdx.x == 0){
    int acc = 0;
    for (int i = 0; i < NB_SCAN; i++){ int v = partials[i]; partials[i] = acc; acc += v; }
  }
}

__global__ void scan3(int* __restrict__ row_start, const int* __restrict__ partials){
  int i = blockIdx.x * 256 + threadIdx.x;
  if (i < N_NODES) row_start[i] += partials[i >> 10];
  if (i == 0) row_start[N_NODES] = E_TOT;
}

__global__ void fill_csr(const int* __restrict__ src, const int* __restrict__ dst,
                         const int* __restrict__ row_start, int* __restrict__ cursor,
                         int* __restrict__ col){
  int e = blockIdx.x * 256 + threadIdx.x;
  if (e >= E_TOT) return;
  int d = dst[e];
  int p = atomicAdd(&cursor[d], 1);
  col[row_start[d] + p] = src[e];
}

// ---------- u = in @ wl_top  (per-node transform; linearity trick) ----------
__global__ void node_matmul(const float* __restrict__ in, int sin, int cin,
                            const float* __restrict__ wl, int coutShift,
                            float* __restrict__ u, int n){
  int cout = 1 << coutShift;
  long long idx = (long long)blockIdx.x * 256 + threadIdx.x;
  if (idx >= (long long)n * cout) return;
  int node = (int)(idx >> coutShift);
  int c = (int)idx & (cout - 1);
  const float* row = in + (long long)node * sin;
  float acc = 0.f;
  for (int k = 0; k < cin; ++k) acc = fmaf(row[k], wl[k * cout + c], acc);
  u[idx] = acc;
}

// ---------- CSR pull edge aggregation: agg[d,c] = max_e u[src_e,c] + dpos.wl_bot ----------
template<int COUT>
__global__ __launch_bounds__(256) void edge_agg(
    const float* __restrict__ u, const float* __restrict__ pos,
    const float* __restrict__ wl, int cin,
    const int* __restrict__ row_start, const int* __restrict__ col,
    float* __restrict__ agg, int n){
  constexpr int CPL = (COUT + 63) / 64;
  int wave = threadIdx.x >> 6;
  int lane = threadIdx.x & 63;
  int d = blockIdx.x * 4 + wave;
  if (d >= n) return;
  bool act = (lane < COUT) || (COUT >= 64);
  const float* wb = wl + (long long)cin * COUT;
  float w0[CPL], w1[CPL], w2[CPL], acc[CPL];
  #pragma unroll
  for (int j = 0; j < CPL; j++){
    int c = lane + 64 * j;
    w0[j] = act ? wb[0 * COUT + c] : 0.f;
    w1[j] = act ? wb[1 * COUT + c] : 0.f;
    w2[j] = act ? wb[2 * COUT + c] : 0.f;
    acc[j] = -INFINITY;
  }
  float px = pos[d * 3 + 0], py = pos[d * 3 + 1], pz = pos[d * 3 + 2];
  int e0 = row_start[d], e1 = row_start[d + 1];
  for (int e = e0; e < e1; ++e){
    int s = col[e];
    float dx = pos[s * 3 + 0] - px;
    float dy = pos[s * 3 + 1] - py;
    float dz = pos[s * 3 + 2] - pz;
    #pragma unroll
    for (int j = 0; j < CPL; j++){
      int c = lane + 64 * j;
      float v = u[(long long)s * COUT + c]; // in-bounds even for idle lanes (buffer is N*128)
      float h = fmaf(dx, w0[j], fmaf(dy, w1[j], fmaf(dz, w2[j], v)));
      acc[j] = fmaxf(acc[j], h);
    }
  }
  if (act){
    #pragma unroll
    for (int j = 0; j < CPL; j++)
      agg[(long long)d * COUT + lane + 64 * j] = acc[j];
  }
}

// ---------- y = finite_fix(agg) @ wg, in place (each wave owns 8 rows) ----------
template<int COUT>
__global__ __launch_bounds__(256) void apply_wg(float* __restrict__ agg,
                                                const float* __restrict__ wg, int n){
  constexpr int R = 8;
  constexpr int CPL = (COUT + 63) / 64;
  __shared__ float lds[4][R * COUT];
  int wave = threadIdx.x >> 6, lane = threadIdx.x & 63;
  int base = (blockIdx.x * 4 + wave) * R;
  bool wact = base < n;
  if (wact){
    for (int i = lane; i < R * COUT; i += 64){
      int row = base + i / COUT;
      float v = (row < n) ? agg[(long long)base * COUT + i] : 0.f;
      lds[wave][i] = isfinite(v) ? v : 0.f;
    }
  }
  __syncthreads();
  if (!wact) return;
  bool act = (lane < COUT) || (COUT >= 64);
  float acc[CPL][R];
  #pragma unroll
  for (int j = 0; j < CPL; j++)
    #pragma unroll
    for (int r = 0; r < R; r++) acc[j][r] = 0.f;
  if (act){
    const float4* l4 = (const float4*)lds[wave];
    for (int k = 0; k < COUT; k += 4){
      float4 wv[CPL];
      #pragma unroll
      for (int j = 0; j < CPL; j++){
        int c = lane + 64 * j;
        wv[j].x = wg[(k + 0) * COUT + c];
        wv[j].y = wg[(k + 1) * COUT + c];
        wv[j].z = wg[(k + 2) * COUT + c];
        wv[j].w = wg[(k + 3) * COUT + c];
      }
      #pragma unroll
      for (int r = 0; r < R; r++){
        float4 a = l4[(r * COUT + k) >> 2];
        #pragma unroll
        for (int j = 0; j < CPL; j++)
          acc[j][r] = fmaf(a.x, wv[j].x, fmaf(a.y, wv[j].y,
                      fmaf(a.z, wv[j].z, fmaf(a.w, wv[j].w, acc[j][r]))));
      }
    }
    for (int r = 0; r < R; r++){
      int row = base + r;
      if (row < n){
        #pragma unroll
        for (int j = 0; j < CPL; j++)
          agg[(long long)row * COUT + lane + 64 * j] = acc[j][r];
      }
    }
  }
}

// ---------- BN statistics (sum / sumsq per channel) ----------
__global__ void stats_kernel(const float* __restrict__ y, int cout, int n,
                             float* __restrict__ stats){
  int c = threadIdx.x;
  if (c >= cout) return;
  int r0 = blockIdx.x * 512;
  int r1 = min(r0 + 512, n);
  float s = 0.f, q = 0.f;
  for (int r = r0; r < r1; ++r){
    float v = y[(long long)r * cout + c];
    s += v; q += v * v;
  }
  atomicAdd(&stats[c], s);
  atomicAdd(&stats[128 + c], q);
}

__global__ void bn_finalize(const float* __restrict__ stats, const float* __restrict__ g,
                            const float* __restrict__ b, int cout, float invn,
                            float* __restrict__ ss){
  int c = threadIdx.x;
  if (c >= cout) return;
  float mean = stats[c] * invn;
  float var = fmaxf(stats[128 + c] * invn - mean * mean, 0.f);
  float sc = g[c] * rsqrtf(var + 1e-5f);
  ss[c] = sc;
  ss[128 + c] = b[c] - mean * sc;
}

__global__ void bn_elu_apply(const float* __restrict__ y, const float* __restrict__ ss,
                             const float* __restrict__ resid, float* __restrict__ dest,
                             int coutMask, long long total){
  long long i = (long long)blockIdx.x * 256 + threadIdx.x;
  if (i >= total) return;
  int c = (int)i & coutMask;
  float v = fmaf(y[i], ss[c], ss[128 + c]);
  v = v > 0.f ? v : expm1f(v);
  if (resid) v += resid[i];
  dest[i] = v;
}

// ---------- pool5 ----------
__global__ void pool5_a(const float* __restrict__ pos, const int* __restrict__ batch,
                        int* __restrict__ clus, float* __restrict__ cnt,
                        float* __restrict__ psum){
  int i = blockIdx.x * 256 + threadIdx.x;
  if (i >= N_NODES) return;
  int cx = min(max((int)floorf(pos[i * 3 + 0] * 8.f), 0), 7);
  int cy = min(max((int)floorf(pos[i * 3 + 1] * 8.f), 0), 7);
  int cl = batch[i] * 64 + cx * 8 + cy;
  clus[i] = cl;
  atomicAdd(&cnt[cl], 1.f);
  atomicAdd(&psum[cl * 3 + 0], pos[i * 3 + 0]);
  atomicAdd(&psum[cl * 3 + 1], pos[i * 3 + 1]);
  atomicAdd(&psum[cl * 3 + 2], pos[i * 3 + 2]);
}

__global__ void pool5_b(const float* __restrict__ h, const int* __restrict__ clus,
                        unsigned* __restrict__ hce){
  long long idx = (long long)blockIdx.x * 256 + threadIdx.x;
  if (idx >= (long long)N_NODES * 128) return;
  int node = (int)(idx >> 7), c = (int)idx & 127;
  atomicMax(&hce[clus[node] * 128 + c], fenc(h[idx]));
}

__global__ void pool5_c(const unsigned* __restrict__ hce, const float* __restrict__ cnt,
                        const float* __restrict__ psum, float* __restrict__ hcf,
                        float* __restrict__ posc, int* __restrict__ pf){
  int d = blockIdx.x, c = threadIdx.x;
  float v = fdec(hce[d * 128 + c]);
  hcf[d * 128 + c] = isfinite(v) ? v : 0.f;
  if (c < 3) posc[d * 3 + c] = psum[d * 3 + c] / fmaxf(cnt[d], 1.f);
  if (c == 0) pf[d * 64 + (d & 63)] = 1;   // coarse self-loop
}

__global__ void pair_edges(const int* __restrict__ src, const int* __restrict__ dst,
                           const int* __restrict__ clus, int* __restrict__ pf){
  int e = blockIdx.x * 256 + threadIdx.x;
  if (e >= E_TOT) return;
  int cs = clus[src[e]], cd = clus[dst[e]];
  pf[cd * 64 + (cs & 63)] = 1;
}

// ---------- coarse conv: dedup'd pairs, fused agg@wg ----------
__global__ __launch_bounds__(128) void coarse_conv(
    const float* __restrict__ u2, const float* __restrict__ posc,
    const float* __restrict__ wl, const int* __restrict__ pf,
    const float* __restrict__ wg, float* __restrict__ y2){
  __shared__ float sagg[128];
  int d = blockIdx.x, c = threadIdx.x;
  int g = d >> 6;
  float px = posc[d * 3 + 0], py = posc[d * 3 + 1], pz = posc[d * 3 + 2];
  const float* wb = wl + 128 * 128;  // rows 128..130 of (131,128)
  float w0 = wb[c], w1 = wb[128 + c], w2 = wb[256 + c];
  float acc = -INFINITY;
  for (int j = 0; j < 64; ++j){
    if (pf[d * 64 + j]){
      int s = g * 64 + j;
      float dx = posc[s * 3 + 0] - px;
      float dy = posc[s * 3 + 1] - py;
      float dz = posc[s * 3 + 2] - pz;
      float h = fmaf(dx, w0, fmaf(dy, w1, fmaf(dz, w2, u2[s * 128 + c])));
      acc = fmaxf(acc, h);
    }
  }
  sagg[c] = isfinite(acc) ? acc : 0.f;
  __syncthreads();
  float y = 0.f;
  for (int k = 0; k < 128; ++k) y = fmaf(sagg[k], wg[k * 128 + c], y);
  y2[d * 128 + c] = y;
}

// ---------- pool7 ----------
__global__ void pool7(const float* __restrict__ c7, const float* __restrict__ posc,
                      unsigned* __restrict__ xoe){
  int i = blockIdx.x, c = threadIdx.x;
  int g = i >> 6;
  int cx = min(max((int)floorf(posc[i * 3 + 0] * 4.f), 0), 3);
  int cy = min(max((int)floorf(posc[i * 3 + 1] * 4.f), 0), 3);
  int cl2 = g * 16 + cx * 4 + cy;
  atomicMax(&xoe[cl2 * 128 + c], fenc(c7[i * 128 + c]));
}

// ---------- final FC: (8,2048) @ (2048,10) ----------
__global__ void fc_kernel(const unsigned* __restrict__ xoe, const float* __restrict__ wfc,
                          float* __restrict__ out){
  int o = blockIdx.x;           // 0..79
  int b = o / 10, cls = o % 10;
  int lane = threadIdx.x;
  float s = 0.f;
  for (int k = lane; k < 2048; k += 64){
    float v = fdec(xoe[b * 2048 + k]);
    v = isfinite(v) ? v : 0.f;
    s = fmaf(v, wfc[k * 10 + cls], s);
  }
  for (int off = 32; off > 0; off >>= 1) s += __shfl_down(s, off, 64);
  if (lane == 0) out[o] = s;
}

// ---------- host ----------
extern "C" void kernel_launch(void* const* d_in, const int* in_sizes, int n_in,
                              void* d_out, int out_size, void* d_ws, size_t ws_size,
                              hipStream_t stream){
  (void)in_sizes; (void)n_in; (void)out_size; (void)ws_size;
  const float* X   = (const float*)d_in[0];
  const float* POS = (const float*)d_in[1];
  const int*   SRC = (const int*)d_in[2];
  const int*   DST = (const int*)d_in[3];
  const int*   BAT = (const int*)d_in[4];
  const float* WL[7]; const float* WG[7]; const float* GG[7]; const float* BB[7];
  for (int i = 0; i < 7; i++){
    WL[i] = (const float*)d_in[5 + 4 * i];
    WG[i] = (const float*)d_in[6 + 4 * i];
    GG[i] = (const float*)d_in[7 + 4 * i];
    BB[i] = (const float*)d_in[8 + 4 * i];
  }
  const float* WFC = (const float*)d_in[33];
  float* OUT = (float*)d_out;

  // workspace layout (floats)
  float* wsf = (float*)d_ws;
  size_t o = 0;
  auto alloc = [&](size_t nf){ float* p = wsf + o; o += nf; return p; };
  float* F0   = alloc((size_t)N_NODES * 128);
  float* F1   = alloc((size_t)N_NODES * 128);
  float* U    = alloc((size_t)N_NODES * 128);
  float* AG   = alloc((size_t)N_NODES * 128);
  float* HCF  = alloc(C1 * 128);
  float* POSC = alloc(2048);
  float* C6B  = alloc(C1 * 128);
  float* C7B  = alloc(C1 * 128);
  float* U2   = alloc(C1 * 128);
  float* Y2   = alloc(C1 * 128);
  float* SS   = alloc(9 * 256);
  int* COL  = (int*)alloc(E_TOT);
  int* ROWS = (int*)alloc(N_NODES + 8);
  int* PART = (int*)alloc(256);
  int* CLUS = (int*)alloc(N_NODES);
  // ---- zero zone (everything below is zeroed at call start) ----
  int* ZZ = (int*)(wsf + o);
  int*      DEG  = (int*)alloc(N_NODES);
  int*      CUR  = (int*)alloc(N_NODES);
  float*    STAT = alloc(9 * 256);
  unsigned* HCE  = (unsigned*)alloc(C1 * 128);
  float*    CNT  = alloc(512);
  float*    PSUM = alloc(2048);
  int*      PF   = (int*)alloc(C1 * 64);
  unsigned* XOE  = (unsigned*)alloc(128 * 128);
  int zz_n = (int)((int*)(wsf + o) - ZZ);

  zero_kernel<<<cdiv(zz_n, 256), 256, 0, stream>>>(ZZ, zz_n);

  // CSR build
  count_deg<<<cdiv(E_TOT, 256), 256, 0, stream>>>(DST, DEG);
  scan1<<<NB_SCAN, 256, 0, stream>>>(DEG, ROWS, PART);
  scan2<<<1, 1, 0, stream>>>(PART);
  scan3<<<cdiv(N_NODES, 256), 256, 0, stream>>>(ROWS, PART);
  fill_csr<<<cdiv(E_TOT, 256), 256, 0, stream>>>(SRC, DST, ROWS, CUR, COL);

  auto fine_layer = [&](const float* in, int sin, int cin, int cout, int li,
                        const float* resid, float* dest){
    int csh = (cout == 16) ? 4 : (cout == 64) ? 6 : 7;
    node_matmul<<<cdiv(N_NODES * cout, 256), 256, 0, stream>>>(in, sin, cin, WL[li], csh, U, N_NODES);
    dim3 gE(cdiv(N_NODES, 4)), bE(256);
    dim3 gW(cdiv(N_NODES, 32)), bW(256);
    if (cout == 16){
      edge_agg<16><<<gE, bE, 0, stream>>>(U, POS, WL[li], cin, ROWS, COL, AG, N_NODES);
      apply_wg<16><<<gW, bW, 0, stream>>>(AG, WG[li], N_NODES);
    } else if (cout == 64){
      edge_agg<64><<<gE, bE, 0, stream>>>(U, POS, WL[li], cin, ROWS, COL, AG, N_NODES);
      apply_wg<64><<<gW, bW, 0, stream>>>(AG, WG[li], N_NODES);
    } else {
      edge_agg<128><<<gE, bE, 0, stream>>>(U, POS, WL[li], cin, ROWS, COL, AG, N_NODES);
      apply_wg<128><<<gW, bW, 0, stream>>>(AG, WG[li], N_NODES);
    }
    stats_kernel<<<cdiv(N_NODES, 512), 128, 0, stream>>>(AG, cout, N_NODES, STAT + li * 256);
    bn_finalize<<<1, 128, 0, stream>>>(STAT + li * 256, GG[li], BB[li], cout, 1.f / N_NODES, SS + li * 256);
    bn_elu_apply<<<cdiv(N_NODES * cout, 256), 256, 0, stream>>>(
        AG, SS + li * 256, resid, dest, cout - 1, (long long)N_NODES * cout);
  };

  fine_layer(X,  1,  1,  16, 0, nullptr, F0);
  fine_layer(F0, 16, 16, 64, 1, nullptr, F1);
  fine_layer(F1, 64, 64, 64, 2, nullptr, F0);
  fine_layer(F0, 64, 64, 64, 3, F1,      F1);   // + residual (sc = layer2 out)
  fine_layer(F1, 64, 64, 128, 4, nullptr, F0);

  // pool5
  pool5_a<<<cdiv(N_NODES, 256), 256, 0, stream>>>(POS, BAT, CLUS, CNT, PSUM);
  pool5_b<<<cdiv(N_NODES * 128, 256), 256, 0, stream>>>(F0, CLUS, HCE);
  pool5_c<<<C1, 128, 0, stream>>>(HCE, CNT, PSUM, HCF, POSC, PF);
  pair_edges<<<cdiv(E_TOT, 256), 256, 0, stream>>>(SRC, DST, CLUS, PF);

  auto coarse_layer = [&](const float* in, int li, const float* resid, float* dest){
    node_matmul<<<cdiv(C1 * 128, 256), 256, 0, stream>>>(in, 128, 128, WL[li], 7, U2, C1);
    coarse_conv<<<C1, 128, 0, stream>>>(U2, POSC, WL[li], PF, WG[li], Y2);
    stats_kernel<<<1, 128, 0, stream>>>(Y2, 128, C1, STAT + li * 256);
    bn_finalize<<<1, 128, 0, stream>>>(STAT + li * 256, GG[li], BB[li], 128, 1.f / C1, SS + li * 256);
    bn_elu_apply<<<cdiv(C1 * 128, 256), 256, 0, stream>>>(
        Y2, SS + li * 256, resid, dest, 127, (long long)C1 * 128);
  };

  coarse_layer(HCF, 5, nullptr, C6B);
  coarse_layer(C6B, 6, HCF,    C7B);   // + residual (sc2 = hc)

  pool7<<<C1, 128, 0, stream>>>(C7B, POSC, XOE);
  fc_kernel<<<80, 64, 0, stream>>>(XOE, WFC, OUT);
}

// Round 2
// 1927.824 us; speedup vs baseline: 1.5457x; 1.5457x over previous
//
#include <hip/hip_runtime.h>
#include <math.h>

#define N_NODES 100000
#define E_TOT   1700000
#define C1      512
#define NB_SCAN 98   // ceil(100000/1024)

static inline int cdiv(int a, int b){ return (a + b - 1) / b; }

// ---------- ordered-float encoding for atomic max ----------
__device__ __forceinline__ unsigned fenc(float f){
  unsigned u = __float_as_uint(f);
  return (u >> 31) ? ~u : (u | 0x80000000u);
}
__device__ __forceinline__ float fdec(unsigned e){
  return (e & 0x80000000u) ? __uint_as_float(e ^ 0x80000000u) : __uint_as_float(~e);
}
// note: fdec(0) = NaN  -> "empty segment" -> replaced by 0 like the reference

// ---------- utility ----------
__global__ void zero_kernel(int* __restrict__ p, int n){
  int i = blockIdx.x * 256 + threadIdx.x;
  if (i < n) p[i] = 0;
}

// ---------- CSR build (dst-indexed), reused by all 5 fine layers ----------
__global__ void count_deg(const int* __restrict__ dst, int* __restrict__ deg){
  int e = blockIdx.x * 256 + threadIdx.x;
  if (e < E_TOT) atomicAdd(&deg[dst[e]], 1);
}

__global__ void scan1(const int* __restrict__ deg, int* __restrict__ row_start,
                      int* __restrict__ partials){
  __shared__ int sm[256];
  int t = threadIdx.x, b = blockIdx.x;
  int base = b * 1024 + t * 4;
  int d0 = (base + 0 < N_NODES) ? deg[base + 0] : 0;
  int d1 = (base + 1 < N_NODES) ? deg[base + 1] : 0;
  int d2 = (base + 2 < N_NODES) ? deg[base + 2] : 0;
  int d3 = (base + 3 < N_NODES) ? deg[base + 3] : 0;
  int s = d0 + d1 + d2 + d3;
  sm[t] = s; __syncthreads();
  for (int off = 1; off < 256; off <<= 1){
    int v = (t >= off) ? sm[t - off] : 0;
    __syncthreads();
    sm[t] += v;
    __syncthreads();
  }
  int excl = sm[t] - s;
  if (base + 0 < N_NODES) row_start[base + 0] = excl;
  if (base + 1 < N_NODES) row_start[base + 1] = excl + d0;
  if (base + 2 < N_NODES) row_start[base + 2] = excl + d0 + d1;
  if (base + 3 < N_NODES) row_start[base + 3] = excl + d0 + d1 + d2;
  if (t == 255) partials[b] = sm[255];
}

__global__ void scan2(int* __restrict__ partials){
  if (threadIdx.x == 0 && blockIdx.x == 0){
    int acc = 0;
    for (int i = 0; i < NB_SCAN; i++){ int v = partials[i]; partials[i] = acc; acc += v; }
  }
}

__global__ void scan3(int* __restrict__ row_start, const int* __restrict__ partials){
  int i = blockIdx.x * 256 + threadIdx.x;
  if (i < N_NODES) row_start[i] += partials[i >> 10];
  if (i == 0) row_start[N_NODES] = E_TOT;
}

__global__ void fill_csr(const int* __restrict__ src, const int* __restrict__ dst,
                         const int* __restrict__ row_start, int* __restrict__ cursor,
                         int* __restrict__ col){
  int e = blockIdx.x * 256 + threadIdx.x;
  if (e >= E_TOT) return;
  int d = dst[e];
  int p = atomicAdd(&cursor[d], 1);
  col[row_start[d] + p] = src[e];
}

// ---------- tiled GEMM: out[n,COUT] = fix(in[n,CIN]) @ w  (+fused BN stats) ----
// One wave per 8 contiguous rows, staged in LDS via float4; weight float4 loads
// amortized over 8 independent accumulators per channel.
template<int CIN, int COUT, bool FIX, bool STATS>
__global__ __launch_bounds__(256) void gemm_tile(
    const float* __restrict__ in, const float* __restrict__ w,
    float* __restrict__ out, float* __restrict__ stat, int n){
  constexpr int R = 8;
  constexpr int CPL = (COUT + 63) / 64;
  __shared__ float lds[4][R * CIN];
  __shared__ float sred[STATS ? 8 * COUT : 1];
  int wave = threadIdx.x >> 6, lane = threadIdx.x & 63;
  int base = (blockIdx.x * 4 + wave) * R;

  if (base < n){
    const float4* src4 = (const float4*)(in + (size_t)base * CIN);
    float4* dst4 = (float4*)lds[wave];
    int n4 = min(R, n - base) * CIN / 4;
    for (int i = lane; i < R * CIN / 4; i += 64){
      float4 v = (i < n4) ? src4[i] : make_float4(0.f, 0.f, 0.f, 0.f);
      if (FIX){
        v.x = isfinite(v.x) ? v.x : 0.f; v.y = isfinite(v.y) ? v.y : 0.f;
        v.z = isfinite(v.z) ? v.z : 0.f; v.w = isfinite(v.w) ? v.w : 0.f;
      }
      dst4[i] = v;
    }
  }
  __syncthreads();

  bool act = (COUT >= 64) || (lane < COUT);
  float acc[CPL][R];
  #pragma unroll
  for (int j = 0; j < CPL; j++)
    #pragma unroll
    for (int r = 0; r < R; r++) acc[j][r] = 0.f;

  if (base < n && act){
    const float4* l4 = (const float4*)lds[wave];
    for (int k = 0; k < CIN; k += 4){
      float4 wv[CPL];
      #pragma unroll
      for (int j = 0; j < CPL; j++){
        int c = lane + 64 * j;
        wv[j].x = w[(k + 0) * COUT + c];
        wv[j].y = w[(k + 1) * COUT + c];
        wv[j].z = w[(k + 2) * COUT + c];
        wv[j].w = w[(k + 3) * COUT + c];
      }
      #pragma unroll
      for (int r = 0; r < R; r++){
        float4 a = l4[(r * CIN + k) >> 2];
        #pragma unroll
        for (int j = 0; j < CPL; j++)
          acc[j][r] = fmaf(a.x, wv[j].x, fmaf(a.y, wv[j].y,
                      fmaf(a.z, wv[j].z, fmaf(a.w, wv[j].w, acc[j][r]))));
      }
    }
    int nrows = min(R, n - base);
    for (int r = 0; r < nrows; r++){
      #pragma unroll
      for (int j = 0; j < CPL; j++)
        out[(size_t)(base + r) * COUT + lane + 64 * j] = acc[j][r];
    }
  }

  if (STATS){
    // per-lane row-sums (zero for inactive/out-of-range waves since acc==0)
    #pragma unroll
    for (int j = 0; j < CPL; j++){
      float s = 0.f, q = 0.f;
      #pragma unroll
      for (int r = 0; r < R; r++){ s += acc[j][r]; q += acc[j][r] * acc[j][r]; }
      if (act){
        int c = lane + 64 * j;
        sred[(2 * wave + 0) * COUT + c] = s;
        sred[(2 * wave + 1) * COUT + c] = q;
      }
    }
    __syncthreads();
    int c = threadIdx.x;
    if (c < COUT){
      float S = 0.f, Q = 0.f;
      #pragma unroll
      for (int wv = 0; wv < 4; wv++){
        S += sred[(2 * wv + 0) * COUT + c];
        Q += sred[(2 * wv + 1) * COUT + c];
      }
      atomicAdd(&stat[c], S);
      atomicAdd(&stat[128 + c], Q);
    }
  }
}

// ---------- layer-1 node transform: u[n,16] = x[n] * wl[0,:] ----------
__global__ void node1_kernel(const float* __restrict__ x, const float* __restrict__ wl,
                             float* __restrict__ u){
  int i = blockIdx.x * 256 + threadIdx.x;
  if (i >= N_NODES * 16) return;
  u[i] = x[i >> 4] * wl[i & 15];
}

// ---------- generic node matmul (coarse layers only, n=512) ----------
__global__ void node_matmul(const float* __restrict__ in, int sin, int cin,
                            const float* __restrict__ wl, int coutShift,
                            float* __restrict__ u, int n){
  int cout = 1 << coutShift;
  long long idx = (long long)blockIdx.x * 256 + threadIdx.x;
  if (idx >= (long long)n * cout) return;
  int node = (int)(idx >> coutShift);
  int c = (int)idx & (cout - 1);
  const float* row = in + (long long)node * sin;
  float acc = 0.f;
  for (int k = 0; k < cin; ++k) acc = fmaf(row[k], wl[k * cout + c], acc);
  u[idx] = acc;
}

// ---------- CSR pull edge aggregation: agg[d,c] = max_e u[src_e,c] + dpos.wl_bot ----------
template<int COUT>
__global__ __launch_bounds__(256) void edge_agg(
    const float* __restrict__ u, const float* __restrict__ pos,
    const float* __restrict__ wl, int cin,
    const int* __restrict__ row_start, const int* __restrict__ col,
    float* __restrict__ agg, int n){
  constexpr int CPL = (COUT + 63) / 64;
  int wave = threadIdx.x >> 6;
  int lane = threadIdx.x & 63;
  int d = blockIdx.x * 4 + wave;
  if (d >= n) return;
  bool act = (lane < COUT) || (COUT >= 64);
  const float* wb = wl + (long long)cin * COUT;
  float w0[CPL], w1[CPL], w2[CPL], acc[CPL];
  #pragma unroll
  for (int j = 0; j < CPL; j++){
    int c = lane + 64 * j;
    w0[j] = act ? wb[0 * COUT + c] : 0.f;
    w1[j] = act ? wb[1 * COUT + c] : 0.f;
    w2[j] = act ? wb[2 * COUT + c] : 0.f;
    acc[j] = -INFINITY;
  }
  float px = pos[d * 3 + 0], py = pos[d * 3 + 1], pz = pos[d * 3 + 2];
  int e0 = row_start[d], e1 = row_start[d + 1];
  for (int e = e0; e < e1; ++e){
    int s = col[e];
    float dx = pos[s * 3 + 0] - px;
    float dy = pos[s * 3 + 1] - py;
    float dz = pos[s * 3 + 2] - pz;
    #pragma unroll
    for (int j = 0; j < CPL; j++){
      int c = lane + 64 * j;
      float v = u[(long long)s * COUT + c]; // in-bounds even for idle lanes (buffer is N*128)
      float h = fmaf(dx, w0[j], fmaf(dy, w1[j], fmaf(dz, w2[j], v)));
      acc[j] = fmaxf(acc[j], h);
    }
  }
  if (act){
    #pragma unroll
    for (int j = 0; j < CPL; j++)
      agg[(long long)d * COUT + lane + 64 * j] = acc[j];
  }
}

// ---------- BN statistics (coarse layers only) ----------
__global__ void stats_kernel(const float* __restrict__ y, int cout, int n,
                             float* __restrict__ stats){
  int c = threadIdx.x;
  if (c >= cout) return;
  int r0 = blockIdx.x * 512;
  int r1 = min(r0 + 512, n);
  float s = 0.f, q = 0.f;
  for (int r = r0; r < r1; ++r){
    float v = y[(long long)r * cout + c];
    s += v; q += v * v;
  }
  atomicAdd(&stats[c], s);
  atomicAdd(&stats[128 + c], q);
}

__global__ void bn_finalize(const float* __restrict__ stats, const float* __restrict__ g,
                            const float* __restrict__ b, int cout, float invn,
                            float* __restrict__ ss){
  int c = threadIdx.x;
  if (c >= cout) return;
  float mean = stats[c] * invn;
  float var = fmaxf(stats[128 + c] * invn - mean * mean, 0.f);
  float sc = g[c] * rsqrtf(var + 1e-5f);
  ss[c] = sc;
  ss[128 + c] = b[c] - mean * sc;
}

__global__ void bn_elu_apply4(const float4* __restrict__ y, const float* __restrict__ ss,
                              const float4* __restrict__ resid, float4* __restrict__ dest,
                              int coutMask, long long total4){
  long long i = (long long)blockIdx.x * 256 + threadIdx.x;
  if (i >= total4) return;
  int c0 = (int)((i * 4) & coutMask);
  float4 v = y[i];
  v.x = fmaf(v.x, ss[c0 + 0], ss[128 + c0 + 0]);
  v.y = fmaf(v.y, ss[c0 + 1], ss[128 + c0 + 1]);
  v.z = fmaf(v.z, ss[c0 + 2], ss[128 + c0 + 2]);
  v.w = fmaf(v.w, ss[c0 + 3], ss[128 + c0 + 3]);
  v.x = v.x > 0.f ? v.x : expm1f(v.x);
  v.y = v.y > 0.f ? v.y : expm1f(v.y);
  v.z = v.z > 0.f ? v.z : expm1f(v.z);
  v.w = v.w > 0.f ? v.w : expm1f(v.w);
  if (resid){
    float4 r = resid[i];
    v.x += r.x; v.y += r.y; v.z += r.z; v.w += r.w;
  }
  dest[i] = v;
}

// ---------- pool5 ----------
__global__ void pool5_a(const float* __restrict__ pos, const int* __restrict__ batch,
                        int* __restrict__ clus, float* __restrict__ cnt,
                        float* __restrict__ psum){
  int i = blockIdx.x * 256 + threadIdx.x;
  if (i >= N_NODES) return;
  int cx = min(max((int)floorf(pos[i * 3 + 0] * 8.f), 0), 7);
  int cy = min(max((int)floorf(pos[i * 3 + 1] * 8.f), 0), 7);
  int cl = batch[i] * 64 + cx * 8 + cy;
  clus[i] = cl;
  atomicAdd(&cnt[cl], 1.f);
  atomicAdd(&psum[cl * 3 + 0], pos[i * 3 + 0]);
  atomicAdd(&psum[cl * 3 + 1], pos[i * 3 + 1]);
  atomicAdd(&psum[cl * 3 + 2], pos[i * 3 + 2]);
}

__global__ void pool5_b(const float* __restrict__ h, const int* __restrict__ clus,
                        unsigned* __restrict__ hce){
  long long idx = (long long)blockIdx.x * 256 + threadIdx.x;
  if (idx >= (long long)N_NODES * 128) return;
  int node = (int)(idx >> 7), c = (int)idx & 127;
  atomicMax(&hce[clus[node] * 128 + c], fenc(h[idx]));
}

__global__ void pool5_c(const unsigned* __restrict__ hce, const float* __restrict__ cnt,
                        const float* __restrict__ psum, float* __restrict__ hcf,
                        float* __restrict__ posc, int* __restrict__ pf){
  int d = blockIdx.x, c = threadIdx.x;
  float v = fdec(hce[d * 128 + c]);
  hcf[d * 128 + c] = isfinite(v) ? v : 0.f;
  if (c < 3) posc[d * 3 + c] = psum[d * 3 + c] / fmaxf(cnt[d], 1.f);
  if (c == 0) pf[d * 64 + (d & 63)] = 1;   // coarse self-loop
}

__global__ void pair_edges(const int* __restrict__ src, const int* __restrict__ dst,
                           const int* __restrict__ clus, int* __restrict__ pf){
  int e = blockIdx.x * 256 + threadIdx.x;
  if (e >= E_TOT) return;
  int cs = clus[src[e]], cd = clus[dst[e]];
  pf[cd * 64 + (cs & 63)] = 1;
}

// ---------- coarse conv: dedup'd pairs, fused agg@wg ----------
__global__ __launch_bounds__(128) void coarse_conv(
    const float* __restrict__ u2, const float* __restrict__ posc,
    const float* __restrict__ wl, const int* __restrict__ pf,
    const float* __restrict__ wg, float* __restrict__ y2){
  __shared__ float sagg[128];
  int d = blockIdx.x, c = threadIdx.x;
  int g = d >> 6;
  float px = posc[d * 3 + 0], py = posc[d * 3 + 1], pz = posc[d * 3 + 2];
  const float* wb = wl + 128 * 128;  // rows 128..130 of (131,128)
  float w0 = wb[c], w1 = wb[128 + c], w2 = wb[256 + c];
  float acc = -INFINITY;
  for (int j = 0; j < 64; ++j){
    if (pf[d * 64 + j]){
      int s = g * 64 + j;
      float dx = posc[s * 3 + 0] - px;
      float dy = posc[s * 3 + 1] - py;
      float dz = posc[s * 3 + 2] - pz;
      float h = fmaf(dx, w0, fmaf(dy, w1, fmaf(dz, w2, u2[s * 128 + c])));
      acc = fmaxf(acc, h);
    }
  }
  sagg[c] = isfinite(acc) ? acc : 0.f;
  __syncthreads();
  float y = 0.f;
  for (int k = 0; k < 128; ++k) y = fmaf(sagg[k], wg[k * 128 + c], y);
  y2[d * 128 + c] = y;
}

// ---------- pool7 ----------
__global__ void pool7(const float* __restrict__ c7, const float* __restrict__ posc,
                      unsigned* __restrict__ xoe){
  int i = blockIdx.x, c = threadIdx.x;
  int g = i >> 6;
  int cx = min(max((int)floorf(posc[i * 3 + 0] * 4.f), 0), 3);
  int cy = min(max((int)floorf(posc[i * 3 + 1] * 4.f), 0), 3);
  int cl2 = g * 16 + cx * 4 + cy;
  atomicMax(&xoe[cl2 * 128 + c], fenc(c7[i * 128 + c]));
}

// ---------- final FC: (8,2048) @ (2048,10) ----------
__global__ void fc_kernel(const unsigned* __restrict__ xoe, const float* __restrict__ wfc,
                          float* __restrict__ out){
  int o = blockIdx.x;           // 0..79
  int b = o / 10, cls = o % 10;
  int lane = threadIdx.x;
  float s = 0.f;
  for (int k = lane; k < 2048; k += 64){
    float v = fdec(xoe[b * 2048 + k]);
    v = isfinite(v) ? v : 0.f;
    s = fmaf(v, wfc[k * 10 + cls], s);
  }
  for (int off = 32; off > 0; off >>= 1) s += __shfl_down(s, off, 64);
  if (lane == 0) out[o] = s;
}

// ---------- host ----------
extern "C" void kernel_launch(void* const* d_in, const int* in_sizes, int n_in,
                              void* d_out, int out_size, void* d_ws, size_t ws_size,
                              hipStream_t stream){
  (void)in_sizes; (void)n_in; (void)out_size; (void)ws_size;
  const float* X   = (const float*)d_in[0];
  const float* POS = (const float*)d_in[1];
  const int*   SRC = (const int*)d_in[2];
  const int*   DST = (const int*)d_in[3];
  const int*   BAT = (const int*)d_in[4];
  const float* WL[7]; const float* WG[7]; const float* GG[7]; const float* BB[7];
  for (int i = 0; i < 7; i++){
    WL[i] = (const float*)d_in[5 + 4 * i];
    WG[i] = (const float*)d_in[6 + 4 * i];
    GG[i] = (const float*)d_in[7 + 4 * i];
    BB[i] = (const float*)d_in[8 + 4 * i];
  }
  const float* WFC = (const float*)d_in[33];
  float* OUT = (float*)d_out;

  // workspace layout (floats)
  float* wsf = (float*)d_ws;
  size_t o = 0;
  auto alloc = [&](size_t nf){ float* p = wsf + o; o += nf; return p; };
  float* F0   = alloc((size_t)N_NODES * 128);
  float* F1   = alloc((size_t)N_NODES * 128);
  float* U    = alloc((size_t)N_NODES * 128);
  float* AG   = alloc((size_t)N_NODES * 128);
  float* HCF  = alloc(C1 * 128);
  float* POSC = alloc(2048);
  float* C6B  = alloc(C1 * 128);
  float* C7B  = alloc(C1 * 128);
  float* U2   = alloc(C1 * 128);
  float* Y2   = alloc(C1 * 128);
  float* SS   = alloc(9 * 256);
  int* COL  = (int*)alloc(E_TOT);
  int* ROWS = (int*)alloc(N_NODES + 8);
  int* PART = (int*)alloc(256);
  int* CLUS = (int*)alloc(N_NODES);
  // ---- zero zone (everything below is zeroed at call start) ----
  int* ZZ = (int*)(wsf + o);
  int*      DEG  = (int*)alloc(N_NODES);
  int*      CUR  = (int*)alloc(N_NODES);
  float*    STAT = alloc(9 * 256);
  unsigned* HCE  = (unsigned*)alloc(C1 * 128);
  float*    CNT  = alloc(512);
  float*    PSUM = alloc(2048);
  int*      PF   = (int*)alloc(C1 * 64);
  unsigned* XOE  = (unsigned*)alloc(128 * 128);
  int zz_n = (int)((int*)(wsf + o) - ZZ);

  zero_kernel<<<cdiv(zz_n, 256), 256, 0, stream>>>(ZZ, zz_n);

  // CSR build
  count_deg<<<cdiv(E_TOT, 256), 256, 0, stream>>>(DST, DEG);
  scan1<<<NB_SCAN, 256, 0, stream>>>(DEG, ROWS, PART);
  scan2<<<1, 1, 0, stream>>>(PART);
  scan3<<<cdiv(N_NODES, 256), 256, 0, stream>>>(ROWS, PART);
  fill_csr<<<cdiv(E_TOT, 256), 256, 0, stream>>>(SRC, DST, ROWS, CUR, COL);

  dim3 gE(cdiv(N_NODES, 4)), bE(256);
  dim3 gT(cdiv(N_NODES, 32)), bT(256);

  auto bn_tail = [&](int li, int cout, const float* resid, float* dest){
    bn_finalize<<<1, 128, 0, stream>>>(STAT + li * 256, GG[li], BB[li], cout, 1.f / N_NODES, SS + li * 256);
    bn_elu_apply4<<<cdiv(N_NODES * cout / 4, 256), 256, 0, stream>>>(
        (const float4*)AG, SS + li * 256, (const float4*)resid, (float4*)dest,
        cout - 1, (long long)N_NODES * cout / 4);
  };

  // ---- layer 1: 1 -> 16 ----
  node1_kernel<<<cdiv(N_NODES * 16, 256), 256, 0, stream>>>(X, WL[0], U);
  edge_agg<16><<<gE, bE, 0, stream>>>(U, POS, WL[0], 1, ROWS, COL, AG, N_NODES);
  gemm_tile<16, 16, true, true><<<gT, bT, 0, stream>>>(AG, WG[0], AG, STAT + 0 * 256, N_NODES);
  bn_tail(0, 16, nullptr, F0);

  // ---- layer 2: 16 -> 64 ----
  gemm_tile<16, 64, false, false><<<gT, bT, 0, stream>>>(F0, WL[1], U, nullptr, N_NODES);
  edge_agg<64><<<gE, bE, 0, stream>>>(U, POS, WL[1], 16, ROWS, COL, AG, N_NODES);
  gemm_tile<64, 64, true, true><<<gT, bT, 0, stream>>>(AG, WG[1], AG, STAT + 1 * 256, N_NODES);
  bn_tail(1, 64, nullptr, F1);

  // ---- layer 3: 64 -> 64 ----
  gemm_tile<64, 64, false, false><<<gT, bT, 0, stream>>>(F1, WL[2], U, nullptr, N_NODES);
  edge_agg<64><<<gE, bE, 0, stream>>>(U, POS, WL[2], 64, ROWS, COL, AG, N_NODES);
  gemm_tile<64, 64, true, true><<<gT, bT, 0, stream>>>(AG, WG[2], AG, STAT + 2 * 256, N_NODES);
  bn_tail(2, 64, nullptr, F0);

  // ---- layer 4: 64 -> 64 (+ residual = layer-2 output F1) ----
  gemm_tile<64, 64, false, false><<<gT, bT, 0, stream>>>(F0, WL[3], U, nullptr, N_NODES);
  edge_agg<64><<<gE, bE, 0, stream>>>(U, POS, WL[3], 64, ROWS, COL, AG, N_NODES);
  gemm_tile<64, 64, true, true><<<gT, bT, 0, stream>>>(AG, WG[3], AG, STAT + 3 * 256, N_NODES);
  bn_tail(3, 64, F1, F1);

  // ---- layer 5: 64 -> 128 ----
  gemm_tile<64, 128, false, false><<<gT, bT, 0, stream>>>(F1, WL[4], U, nullptr, N_NODES);
  edge_agg<128><<<gE, bE, 0, stream>>>(U, POS, WL[4], 64, ROWS, COL, AG, N_NODES);
  gemm_tile<128, 128, true, true><<<gT, bT, 0, stream>>>(AG, WG[4], AG, STAT + 4 * 256, N_NODES);
  bn_tail(4, 128, nullptr, F0);

  // pool5
  pool5_a<<<cdiv(N_NODES, 256), 256, 0, stream>>>(POS, BAT, CLUS, CNT, PSUM);
  pool5_b<<<cdiv(N_NODES * 128, 256), 256, 0, stream>>>(F0, CLUS, HCE);
  pool5_c<<<C1, 128, 0, stream>>>(HCE, CNT, PSUM, HCF, POSC, PF);
  pair_edges<<<cdiv(E_TOT, 256), 256, 0, stream>>>(SRC, DST, CLUS, PF);

  auto coarse_layer = [&](const float* in, int li, const float* resid, float* dest){
    node_matmul<<<cdiv(C1 * 128, 256), 256, 0, stream>>>(in, 128, 128, WL[li], 7, U2, C1);
    coarse_conv<<<C1, 128, 0, stream>>>(U2, POSC, WL[li], PF, WG[li], Y2);
    stats_kernel<<<1, 128, 0, stream>>>(Y2, 128, C1, STAT + li * 256);
    bn_finalize<<<1, 128, 0, stream>>>(STAT + li * 256, GG[li], BB[li], 128, 1.f / C1, SS + li * 256);
    bn_elu_apply4<<<cdiv(C1 * 128 / 4, 256), 256, 0, stream>>>(
        (const float4*)Y2, SS + li * 256, (const float4*)resid, (float4*)dest,
        127, (long long)C1 * 128 / 4);
  };

  coarse_layer(HCF, 5, nullptr, C6B);
  coarse_layer(C6B, 6, HCF,    C7B);   // + residual (sc2 = hc)

  pool7<<<C1, 128, 0, stream>>>(C7B, POSC, XOE);
  fc_kernel<<<80, 64, 0, stream>>>(XOE, WFC, OUT);
}

// Round 3
// 1767.935 us; speedup vs baseline: 1.6855x; 1.0904x over previous
//
#include <hip/hip_runtime.h>
#include <math.h>

#define N_NODES 100000
#define NPG     12500
#define E_TOT   1700000
#define C1      512
#define NB_SCAN 98   // ceil(100000/1024)

static inline int cdiv(int a, int b){ return (a + b - 1) / b; }

// ---------- ordered-float encoding for atomic max ----------
__device__ __forceinline__ unsigned fenc(float f){
  unsigned u = __float_as_uint(f);
  return (u >> 31) ? ~u : (u | 0x80000000u);
}
__device__ __forceinline__ float fdec(unsigned e){
  return (e & 0x80000000u) ? __uint_as_float(e ^ 0x80000000u) : __uint_as_float(~e);
}
// note: fdec(0) = NaN  -> "empty segment" -> replaced by 0 like the reference

// ---------- utility ----------
__global__ void zero_kernel(int* __restrict__ p, int n){
  int i = blockIdx.x * 256 + threadIdx.x;
  if (i < n) p[i] = 0;
}

// ---------- CSR build (dst-indexed), reused by all 5 fine layers ----------
__global__ void count_deg(const int* __restrict__ dst, int* __restrict__ deg){
  int e = blockIdx.x * 256 + threadIdx.x;
  if (e < E_TOT) atomicAdd(&deg[dst[e]], 1);
}

__global__ void scan1(const int* __restrict__ deg, int* __restrict__ row_start,
                      int* __restrict__ partials){
  __shared__ int sm[256];
  int t = threadIdx.x, b = blockIdx.x;
  int base = b * 1024 + t * 4;
  int d0 = (base + 0 < N_NODES) ? deg[base + 0] : 0;
  int d1 = (base + 1 < N_NODES) ? deg[base + 1] : 0;
  int d2 = (base + 2 < N_NODES) ? deg[base + 2] : 0;
  int d3 = (base + 3 < N_NODES) ? deg[base + 3] : 0;
  int s = d0 + d1 + d2 + d3;
  sm[t] = s; __syncthreads();
  for (int off = 1; off < 256; off <<= 1){
    int v = (t >= off) ? sm[t - off] : 0;
    __syncthreads();
    sm[t] += v;
    __syncthreads();
  }
  int excl = sm[t] - s;
  if (base + 0 < N_NODES) row_start[base + 0] = excl;
  if (base + 1 < N_NODES) row_start[base + 1] = excl + d0;
  if (base + 2 < N_NODES) row_start[base + 2] = excl + d0 + d1;
  if (base + 3 < N_NODES) row_start[base + 3] = excl + d0 + d1 + d2;
  if (t == 255) partials[b] = sm[255];
}

__global__ void scan2(int* __restrict__ partials){
  if (threadIdx.x == 0 && blockIdx.x == 0){
    int acc = 0;
    for (int i = 0; i < NB_SCAN; i++){ int v = partials[i]; partials[i] = acc; acc += v; }
  }
}

__global__ void scan3(int* __restrict__ row_start, const int* __restrict__ partials){
  int i = blockIdx.x * 256 + threadIdx.x;
  if (i < N_NODES) row_start[i] += partials[i >> 10];
  if (i == 0) row_start[N_NODES] = E_TOT;
}

__global__ void fill_csr(const int* __restrict__ src, const int* __restrict__ dst,
                         const int* __restrict__ row_start, int* __restrict__ cursor,
                         int* __restrict__ col){
  int e = blockIdx.x * 256 + threadIdx.x;
  if (e >= E_TOT) return;
  int d = dst[e];
  int p = atomicAdd(&cursor[d], 1);
  col[row_start[d] + p] = src[e];
}

// ---------- tiled GEMM: out[n,COUT] = fix(in[n,CIN]) @ w  (+fused BN stats) ----
template<int CIN, int COUT, bool FIX, bool STATS>
__global__ __launch_bounds__(256) void gemm_tile(
    const float* __restrict__ in, const float* __restrict__ w,
    float* __restrict__ out, float* __restrict__ stat, int n){
  constexpr int R = 8;
  constexpr int CPL = (COUT + 63) / 64;
  __shared__ float lds[4][R * CIN];
  __shared__ float sred[STATS ? 8 * COUT : 1];
  int wave = threadIdx.x >> 6, lane = threadIdx.x & 63;
  int base = (blockIdx.x * 4 + wave) * R;

  if (base < n){
    const float4* src4 = (const float4*)(in + (size_t)base * CIN);
    float4* dst4 = (float4*)lds[wave];
    int n4 = min(R, n - base) * CIN / 4;
    for (int i = lane; i < R * CIN / 4; i += 64){
      float4 v = (i < n4) ? src4[i] : make_float4(0.f, 0.f, 0.f, 0.f);
      if (FIX){
        v.x = isfinite(v.x) ? v.x : 0.f; v.y = isfinite(v.y) ? v.y : 0.f;
        v.z = isfinite(v.z) ? v.z : 0.f; v.w = isfinite(v.w) ? v.w : 0.f;
      }
      dst4[i] = v;
    }
  }
  __syncthreads();

  bool act = (COUT >= 64) || (lane < COUT);
  float acc[CPL][R];
  #pragma unroll
  for (int j = 0; j < CPL; j++)
    #pragma unroll
    for (int r = 0; r < R; r++) acc[j][r] = 0.f;

  if (base < n && act){
    const float4* l4 = (const float4*)lds[wave];
    for (int k = 0; k < CIN; k += 4){
      float4 wv[CPL];
      #pragma unroll
      for (int j = 0; j < CPL; j++){
        int c = lane + 64 * j;
        wv[j].x = w[(k + 0) * COUT + c];
        wv[j].y = w[(k + 1) * COUT + c];
        wv[j].z = w[(k + 2) * COUT + c];
        wv[j].w = w[(k + 3) * COUT + c];
      }
      #pragma unroll
      for (int r = 0; r < R; r++){
        float4 a = l4[(r * CIN + k) >> 2];
        #pragma unroll
        for (int j = 0; j < CPL; j++)
          acc[j][r] = fmaf(a.x, wv[j].x, fmaf(a.y, wv[j].y,
                      fmaf(a.z, wv[j].z, fmaf(a.w, wv[j].w, acc[j][r]))));
      }
    }
    int nrows = min(R, n - base);
    for (int r = 0; r < nrows; r++){
      #pragma unroll
      for (int j = 0; j < CPL; j++)
        out[(size_t)(base + r) * COUT + lane + 64 * j] = acc[j][r];
    }
  }

  if (STATS){
    #pragma unroll
    for (int j = 0; j < CPL; j++){
      float s = 0.f, q = 0.f;
      #pragma unroll
      for (int r = 0; r < R; r++){ s += acc[j][r]; q += acc[j][r] * acc[j][r]; }
      if (act){
        int c = lane + 64 * j;
        sred[(2 * wave + 0) * COUT + c] = s;
        sred[(2 * wave + 1) * COUT + c] = q;
      }
    }
    __syncthreads();
    int c = threadIdx.x;
    if (c < COUT){
      float S = 0.f, Q = 0.f;
      #pragma unroll
      for (int wv = 0; wv < 4; wv++){
        S += sred[(2 * wv + 0) * COUT + c];
        Q += sred[(2 * wv + 1) * COUT + c];
      }
      atomicAdd(&stat[c], S);
      atomicAdd(&stat[128 + c], Q);
    }
  }
}

// ---------- layer-1 node transform: u[n,16] = x[n] * wl[0,:] ----------
__global__ void node1_kernel(const float* __restrict__ x, const float* __restrict__ wl,
                             float* __restrict__ u){
  int i = blockIdx.x * 256 + threadIdx.x;
  if (i >= N_NODES * 16) return;
  u[i] = x[i >> 4] * wl[i & 15];
}

// ---------- generic node matmul (coarse layers only, n=512) ----------
__global__ void node_matmul(const float* __restrict__ in, int sin, int cin,
                            const float* __restrict__ wl, int coutShift,
                            float* __restrict__ u, int n){
  int cout = 1 << coutShift;
  long long idx = (long long)blockIdx.x * 256 + threadIdx.x;
  if (idx >= (long long)n * cout) return;
  int node = (int)(idx >> coutShift);
  int c = (int)idx & (cout - 1);
  const float* row = in + (long long)node * sin;
  float acc = 0.f;
  for (int k = 0; k < cin; ++k) acc = fmaf(row[k], wl[k * cout + c], acc);
  u[idx] = acc;
}

// ---------- CSR pull edge aggregation (XCD-swizzled, 64 channels/pass) ------
// agg[d, coff+lane] = max_e { u[src_e, coff+lane] + dpos_e . w3[:, coff+lane] }
// grid = 8 graphs x (NPG/4) blocks; blockIdx&7 = graph -> lands on one XCD,
// keeping that graph's u-slice (<=3.2 MB @64ch) resident in its 4 MB L2.
template<int CH>
__global__ __launch_bounds__(256) void edge_agg(
    const float* __restrict__ u, int ustride, int coff,
    const float* __restrict__ pos,
    const float* __restrict__ w3,   // = wl + cin*cout : rows (3, cout)
    int cout,
    const int* __restrict__ row_start, const int* __restrict__ col,
    float* __restrict__ agg){
  int wave = threadIdx.x >> 6, lane = threadIdx.x & 63;
  int g = blockIdx.x & 7;
  int d = g * NPG + (blockIdx.x >> 3) * 4 + wave;   // NPG/4 divides evenly
  bool act = (CH >= 64) || (lane < CH);
  int c = coff + (act ? lane : 0);
  float w0 = w3[c], w1 = w3[cout + c], w2 = w3[2 * cout + c];
  float px = pos[d * 3 + 0], py = pos[d * 3 + 1], pz = pos[d * 3 + 2];
  int e0 = row_start[d], e1 = row_start[d + 1];
  float acc0 = -INFINITY, acc1 = -INFINITY;
  for (int eb = e0; eb < e1; eb += 64){
    int m = min(64, e1 - eb);
    int sv = col[eb + min(lane, m - 1)];   // lane-parallel index preload
    for (int j = 0; j < m; j += 2){
      int sa = __shfl(sv, j, 64);
      int sb = __shfl(sv, min(j + 1, m - 1), 64);  // dup tail: idempotent for max
      float ax = pos[sa * 3 + 0] - px, ay = pos[sa * 3 + 1] - py, az = pos[sa * 3 + 2] - pz;
      float bx = pos[sb * 3 + 0] - px, by = pos[sb * 3 + 1] - py, bz = pos[sb * 3 + 2] - pz;
      float va = u[(size_t)sa * ustride + coff + lane];
      float vb = u[(size_t)sb * ustride + coff + lane];
      acc0 = fmaxf(acc0, fmaf(ax, w0, fmaf(ay, w1, fmaf(az, w2, va))));
      acc1 = fmaxf(acc1, fmaf(bx, w0, fmaf(by, w1, fmaf(bz, w2, vb))));
    }
  }
  if (act) agg[(size_t)d * cout + coff + lane] = fmaxf(acc0, acc1);
}

// ---------- BN statistics (coarse layers only) ----------
__global__ void stats_kernel(const float* __restrict__ y, int cout, int n,
                             float* __restrict__ stats){
  int c = threadIdx.x;
  if (c >= cout) return;
  int r0 = blockIdx.x * 512;
  int r1 = min(r0 + 512, n);
  float s = 0.f, q = 0.f;
  for (int r = r0; r < r1; ++r){
    float v = y[(long long)r * cout + c];
    s += v; q += v * v;
  }
  atomicAdd(&stats[c], s);
  atomicAdd(&stats[128 + c], q);
}

__global__ void bn_finalize(const float* __restrict__ stats, const float* __restrict__ g,
                            const float* __restrict__ b, int cout, float invn,
                            float* __restrict__ ss){
  int c = threadIdx.x;
  if (c >= cout) return;
  float mean = stats[c] * invn;
  float var = fmaxf(stats[128 + c] * invn - mean * mean, 0.f);
  float sc = g[c] * rsqrtf(var + 1e-5f);
  ss[c] = sc;
  ss[128 + c] = b[c] - mean * sc;
}

__global__ void bn_elu_apply4(const float4* __restrict__ y, const float* __restrict__ ss,
                              const float4* __restrict__ resid, float4* __restrict__ dest,
                              int coutMask, long long total4){
  long long i = (long long)blockIdx.x * 256 + threadIdx.x;
  if (i >= total4) return;
  int c0 = (int)((i * 4) & coutMask);
  float4 v = y[i];
  v.x = fmaf(v.x, ss[c0 + 0], ss[128 + c0 + 0]);
  v.y = fmaf(v.y, ss[c0 + 1], ss[128 + c0 + 1]);
  v.z = fmaf(v.z, ss[c0 + 2], ss[128 + c0 + 2]);
  v.w = fmaf(v.w, ss[c0 + 3], ss[128 + c0 + 3]);
  v.x = v.x > 0.f ? v.x : expm1f(v.x);
  v.y = v.y > 0.f ? v.y : expm1f(v.y);
  v.z = v.z > 0.f ? v.z : expm1f(v.z);
  v.w = v.w > 0.f ? v.w : expm1f(v.w);
  if (resid){
    float4 r = resid[i];
    v.x += r.x; v.y += r.y; v.z += r.z; v.w += r.w;
  }
  dest[i] = v;
}

// ---------- pool5 ----------
__global__ void pool5_a(const float* __restrict__ pos, const int* __restrict__ batch,
                        int* __restrict__ clus, float* __restrict__ cnt,
                        float* __restrict__ psum){
  int i = blockIdx.x * 256 + threadIdx.x;
  if (i >= N_NODES) return;
  int cx = min(max((int)floorf(pos[i * 3 + 0] * 8.f), 0), 7);
  int cy = min(max((int)floorf(pos[i * 3 + 1] * 8.f), 0), 7);
  int cl = batch[i] * 64 + cx * 8 + cy;
  clus[i] = cl;
  atomicAdd(&cnt[cl], 1.f);
  atomicAdd(&psum[cl * 3 + 0], pos[i * 3 + 0]);
  atomicAdd(&psum[cl * 3 + 1], pos[i * 3 + 1]);
  atomicAdd(&psum[cl * 3 + 2], pos[i * 3 + 2]);
}

__global__ void pool5_b(const float* __restrict__ h, const int* __restrict__ clus,
                        unsigned* __restrict__ hce){
  long long idx = (long long)blockIdx.x * 256 + threadIdx.x;
  if (idx >= (long long)N_NODES * 128) return;
  int node = (int)(idx >> 7), c = (int)idx & 127;
  atomicMax(&hce[clus[node] * 128 + c], fenc(h[idx]));
}

__global__ void pool5_c(const unsigned* __restrict__ hce, const float* __restrict__ cnt,
                        const float* __restrict__ psum, float* __restrict__ hcf,
                        float* __restrict__ posc, int* __restrict__ pf){
  int d = blockIdx.x, c = threadIdx.x;
  float v = fdec(hce[d * 128 + c]);
  hcf[d * 128 + c] = isfinite(v) ? v : 0.f;
  if (c < 3) posc[d * 3 + c] = psum[d * 3 + c] / fmaxf(cnt[d], 1.f);
  if (c == 0) pf[d * 64 + (d & 63)] = 1;   // coarse self-loop
}

__global__ void pair_edges(const int* __restrict__ src, const int* __restrict__ dst,
                           const int* __restrict__ clus, int* __restrict__ pf){
  int e = blockIdx.x * 256 + threadIdx.x;
  if (e >= E_TOT) return;
  int cs = clus[src[e]], cd = clus[dst[e]];
  pf[cd * 64 + (cs & 63)] = 1;
}

// ---------- coarse conv: dedup'd pairs, fused agg@wg ----------
__global__ __launch_bounds__(128) void coarse_conv(
    const float* __restrict__ u2, const float* __restrict__ posc,
    const float* __restrict__ wl, const int* __restrict__ pf,
    const float* __restrict__ wg, float* __restrict__ y2){
  __shared__ float sagg[128];
  int d = blockIdx.x, c = threadIdx.x;
  int g = d >> 6;
  float px = posc[d * 3 + 0], py = posc[d * 3 + 1], pz = posc[d * 3 + 2];
  const float* wb = wl + 128 * 128;  // rows 128..130 of (131,128)
  float w0 = wb[c], w1 = wb[128 + c], w2 = wb[256 + c];
  float acc = -INFINITY;
  for (int j = 0; j < 64; ++j){
    if (pf[d * 64 + j]){
      int s = g * 64 + j;
      float dx = posc[s * 3 + 0] - px;
      float dy = posc[s * 3 + 1] - py;
      float dz = posc[s * 3 + 2] - pz;
      float h = fmaf(dx, w0, fmaf(dy, w1, fmaf(dz, w2, u2[s * 128 + c])));
      acc = fmaxf(acc, h);
    }
  }
  sagg[c] = isfinite(acc) ? acc : 0.f;
  __syncthreads();
  float y = 0.f;
  for (int k = 0; k < 128; ++k) y = fmaf(sagg[k], wg[k * 128 + c], y);
  y2[d * 128 + c] = y;
}

// ---------- pool7 ----------
__global__ void pool7(const float* __restrict__ c7, const float* __restrict__ posc,
                      unsigned* __restrict__ xoe){
  int i = blockIdx.x, c = threadIdx.x;
  int g = i >> 6;
  int cx = min(max((int)floorf(posc[i * 3 + 0] * 4.f), 0), 3);
  int cy = min(max((int)floorf(posc[i * 3 + 1] * 4.f), 0), 3);
  int cl2 = g * 16 + cx * 4 + cy;
  atomicMax(&xoe[cl2 * 128 + c], fenc(c7[i * 128 + c]));
}

// ---------- final FC: (8,2048) @ (2048,10) ----------
__global__ void fc_kernel(const unsigned* __restrict__ xoe, const float* __restrict__ wfc,
                          float* __restrict__ out){
  int o = blockIdx.x;           // 0..79
  int b = o / 10, cls = o % 10;
  int lane = threadIdx.x;
  float s = 0.f;
  for (int k = lane; k < 2048; k += 64){
    float v = fdec(xoe[b * 2048 + k]);
    v = isfinite(v) ? v : 0.f;
    s = fmaf(v, wfc[k * 10 + cls], s);
  }
  for (int off = 32; off > 0; off >>= 1) s += __shfl_down(s, off, 64);
  if (lane == 0) out[o] = s;
}

// ---------- host ----------
extern "C" void kernel_launch(void* const* d_in, const int* in_sizes, int n_in,
                              void* d_out, int out_size, void* d_ws, size_t ws_size,
                              hipStream_t stream){
  (void)in_sizes; (void)n_in; (void)out_size; (void)ws_size;
  const float* X   = (const float*)d_in[0];
  const float* POS = (const float*)d_in[1];
  const int*   SRC = (const int*)d_in[2];
  const int*   DST = (const int*)d_in[3];
  const int*   BAT = (const int*)d_in[4];
  const float* WL[7]; const float* WG[7]; const float* GG[7]; const float* BB[7];
  for (int i = 0; i < 7; i++){
    WL[i] = (const float*)d_in[5 + 4 * i];
    WG[i] = (const float*)d_in[6 + 4 * i];
    GG[i] = (const float*)d_in[7 + 4 * i];
    BB[i] = (const float*)d_in[8 + 4 * i];
  }
  const float* WFC = (const float*)d_in[33];
  float* OUT = (float*)d_out;

  // workspace layout (floats)
  float* wsf = (float*)d_ws;
  size_t o = 0;
  auto alloc = [&](size_t nf){ float* p = wsf + o; o += nf; return p; };
  float* F0   = alloc((size_t)N_NODES * 128);
  float* F1   = alloc((size_t)N_NODES * 128);
  float* U    = alloc((size_t)N_NODES * 128);
  float* AG   = alloc((size_t)N_NODES * 128);
  float* HCF  = alloc(C1 * 128);
  float* POSC = alloc(2048);
  float* C6B  = alloc(C1 * 128);
  float* C7B  = alloc(C1 * 128);
  float* U2   = alloc(C1 * 128);
  float* Y2   = alloc(C1 * 128);
  float* SS   = alloc(9 * 256);
  int* COL  = (int*)alloc(E_TOT);
  int* ROWS = (int*)alloc(N_NODES + 8);
  int* PART = (int*)alloc(256);
  int* CLUS = (int*)alloc(N_NODES);
  // ---- zero zone (everything below is zeroed at call start) ----
  int* ZZ = (int*)(wsf + o);
  int*      DEG  = (int*)alloc(N_NODES);
  int*      CUR  = (int*)alloc(N_NODES);
  float*    STAT = alloc(9 * 256);
  unsigned* HCE  = (unsigned*)alloc(C1 * 128);
  float*    CNT  = alloc(512);
  float*    PSUM = alloc(2048);
  int*      PF   = (int*)alloc(C1 * 64);
  unsigned* XOE  = (unsigned*)alloc(128 * 128);
  int zz_n = (int)((int*)(wsf + o) - ZZ);

  zero_kernel<<<cdiv(zz_n, 256), 256, 0, stream>>>(ZZ, zz_n);

  // CSR build
  count_deg<<<cdiv(E_TOT, 256), 256, 0, stream>>>(DST, DEG);
  scan1<<<NB_SCAN, 256, 0, stream>>>(DEG, ROWS, PART);
  scan2<<<1, 1, 0, stream>>>(PART);
  scan3<<<cdiv(N_NODES, 256), 256, 0, stream>>>(ROWS, PART);
  fill_csr<<<cdiv(E_TOT, 256), 256, 0, stream>>>(SRC, DST, ROWS, CUR, COL);

  dim3 gE(8 * (NPG / 4)), bE(256);   // 25000 blocks, blockIdx&7 = graph/XCD
  dim3 gT(cdiv(N_NODES, 32)), bT(256);

  auto bn_tail = [&](int li, int cout, const float* resid, float* dest){
    bn_finalize<<<1, 128, 0, stream>>>(STAT + li * 256, GG[li], BB[li], cout, 1.f / N_NODES, SS + li * 256);
    bn_elu_apply4<<<cdiv(N_NODES * cout / 4, 256), 256, 0, stream>>>(
        (const float4*)AG, SS + li * 256, (const float4*)resid, (float4*)dest,
        cout - 1, (long long)N_NODES * cout / 4);
  };

  // ---- layer 1: 1 -> 16 ----
  node1_kernel<<<cdiv(N_NODES * 16, 256), 256, 0, stream>>>(X, WL[0], U);
  edge_agg<16><<<gE, bE, 0, stream>>>(U, 16, 0, POS, WL[0] + 1 * 16, 16, ROWS, COL, AG);
  gemm_tile<16, 16, true, true><<<gT, bT, 0, stream>>>(AG, WG[0], AG, STAT + 0 * 256, N_NODES);
  bn_tail(0, 16, nullptr, F0);

  // ---- layer 2: 16 -> 64 ----
  gemm_tile<16, 64, false, false><<<gT, bT, 0, stream>>>(F0, WL[1], U, nullptr, N_NODES);
  edge_agg<64><<<gE, bE, 0, stream>>>(U, 64, 0, POS, WL[1] + 16 * 64, 64, ROWS, COL, AG);
  gemm_tile<64, 64, true, true><<<gT, bT, 0, stream>>>(AG, WG[1], AG, STAT + 1 * 256, N_NODES);
  bn_tail(1, 64, nullptr, F1);

  // ---- layer 3: 64 -> 64 ----
  gemm_tile<64, 64, false, false><<<gT, bT, 0, stream>>>(F1, WL[2], U, nullptr, N_NODES);
  edge_agg<64><<<gE, bE, 0, stream>>>(U, 64, 0, POS, WL[2] + 64 * 64, 64, ROWS, COL, AG);
  gemm_tile<64, 64, true, true><<<gT, bT, 0, stream>>>(AG, WG[2], AG, STAT + 2 * 256, N_NODES);
  bn_tail(2, 64, nullptr, F0);

  // ---- layer 4: 64 -> 64 (+ residual = layer-2 output F1) ----
  gemm_tile<64, 64, false, false><<<gT, bT, 0, stream>>>(F0, WL[3], U, nullptr, N_NODES);
  edge_agg<64><<<gE, bE, 0, stream>>>(U, 64, 0, POS, WL[3] + 64 * 64, 64, ROWS, COL, AG);
  gemm_tile<64, 64, true, true><<<gT, bT, 0, stream>>>(AG, WG[3], AG, STAT + 3 * 256, N_NODES);
  bn_tail(3, 64, F1, F1);

  // ---- layer 5: 64 -> 128 (two 64-channel passes so u-slice fits per-XCD L2) ----
  gemm_tile<64, 128, false, false><<<gT, bT, 0, stream>>>(F1, WL[4], U, nullptr, N_NODES);
  edge_agg<64><<<gE, bE, 0, stream>>>(U, 128, 0,  POS, WL[4] + 64 * 128, 128, ROWS, COL, AG);
  edge_agg<64><<<gE, bE, 0, stream>>>(U, 128, 64, POS, WL[4] + 64 * 128, 128, ROWS, COL, AG);
  gemm_tile<128, 128, true, true><<<gT, bT, 0, stream>>>(AG, WG[4], AG, STAT + 4 * 256, N_NODES);
  bn_tail(4, 128, nullptr, F0);

  // pool5
  pool5_a<<<cdiv(N_NODES, 256), 256, 0, stream>>>(POS, BAT, CLUS, CNT, PSUM);
  pool5_b<<<cdiv(N_NODES * 128, 256), 256, 0, stream>>>(F0, CLUS, HCE);
  pool5_c<<<C1, 128, 0, stream>>>(HCE, CNT, PSUM, HCF, POSC, PF);
  pair_edges<<<cdiv(E_TOT, 256), 256, 0, stream>>>(SRC, DST, CLUS, PF);

  auto coarse_layer = [&](const float* in, int li, const float* resid, float* dest){
    node_matmul<<<cdiv(C1 * 128, 256), 256, 0, stream>>>(in, 128, 128, WL[li], 7, U2, C1);
    coarse_conv<<<C1, 128, 0, stream>>>(U2, POSC, WL[li], PF, WG[li], Y2);
    stats_kernel<<<1, 128, 0, stream>>>(Y2, 128, C1, STAT + li * 256);
    bn_finalize<<<1, 128, 0, stream>>>(STAT + li * 256, GG[li], BB[li], 128, 1.f / C1, SS + li * 256);
    bn_elu_apply4<<<cdiv(C1 * 128 / 4, 256), 256, 0, stream>>>(
        (const float4*)Y2, SS + li * 256, (const float4*)resid, (float4*)dest,
        127, (long long)C1 * 128 / 4);
  };

  coarse_layer(HCF, 5, nullptr, C6B);
  coarse_layer(C6B, 6, HCF,    C7B);   // + residual (sc2 = hc)

  pool7<<<C1, 128, 0, stream>>>(C7B, POSC, XOE);
  fc_kernel<<<80, 64, 0, stream>>>(XOE, WFC, OUT);
}

// Round 4
// 1571.422 us; speedup vs baseline: 1.8963x; 1.1251x over previous
//
#include <hip/hip_runtime.h>
#include <math.h>

#define N_NODES 100000
#define NPG     12500
#define E_TOT   1700000
#define C1      512
#define NB_SCAN 98   // ceil(100000/1024)
#define NSTRIPE 64   // stats striping: contention 3125 -> ~49 per address

static inline int cdiv(int a, int b){ return (a + b - 1) / b; }

// ---------- ordered-float encoding for atomic max ----------
__device__ __forceinline__ unsigned fenc(float f){
  unsigned u = __float_as_uint(f);
  return (u >> 31) ? ~u : (u | 0x80000000u);
}
__device__ __forceinline__ float fdec(unsigned e){
  return (e & 0x80000000u) ? __uint_as_float(e ^ 0x80000000u) : __uint_as_float(~e);
}
// note: fdec(0) = NaN  -> "empty segment" -> replaced by 0 like the reference

// ---------- utility ----------
__global__ void zero_kernel(int* __restrict__ p, int n){
  int i = blockIdx.x * 256 + threadIdx.x;
  if (i < n) p[i] = 0;
}

// ---------- CSR build (dst-indexed), reused by all 5 fine layers ----------
__global__ void count_deg(const int* __restrict__ dst, int* __restrict__ deg){
  int e = blockIdx.x * 256 + threadIdx.x;
  if (e < E_TOT) atomicAdd(&deg[dst[e]], 1);
}

__global__ void scan1(const int* __restrict__ deg, int* __restrict__ row_start,
                      int* __restrict__ partials){
  __shared__ int sm[256];
  int t = threadIdx.x, b = blockIdx.x;
  int base = b * 1024 + t * 4;
  int d0 = (base + 0 < N_NODES) ? deg[base + 0] : 0;
  int d1 = (base + 1 < N_NODES) ? deg[base + 1] : 0;
  int d2 = (base + 2 < N_NODES) ? deg[base + 2] : 0;
  int d3 = (base + 3 < N_NODES) ? deg[base + 3] : 0;
  int s = d0 + d1 + d2 + d3;
  sm[t] = s; __syncthreads();
  for (int off = 1; off < 256; off <<= 1){
    int v = (t >= off) ? sm[t - off] : 0;
    __syncthreads();
    sm[t] += v;
    __syncthreads();
  }
  int excl = sm[t] - s;
  if (base + 0 < N_NODES) row_start[base + 0] = excl;
  if (base + 1 < N_NODES) row_start[base + 1] = excl + d0;
  if (base + 2 < N_NODES) row_start[base + 2] = excl + d0 + d1;
  if (base + 3 < N_NODES) row_start[base + 3] = excl + d0 + d1 + d2;
  if (t == 255) partials[b] = sm[255];
}

__global__ void scan2(int* __restrict__ partials){
  if (threadIdx.x == 0 && blockIdx.x == 0){
    int acc = 0;
    for (int i = 0; i < NB_SCAN; i++){ int v = partials[i]; partials[i] = acc; acc += v; }
  }
}

__global__ void scan3(int* __restrict__ row_start, const int* __restrict__ partials){
  int i = blockIdx.x * 256 + threadIdx.x;
  if (i < N_NODES) row_start[i] += partials[i >> 10];
  if (i == 0) row_start[N_NODES] = E_TOT;
}

__global__ void fill_csr(const int* __restrict__ src, const int* __restrict__ dst,
                         const int* __restrict__ row_start, int* __restrict__ cursor,
                         int* __restrict__ col){
  int e = blockIdx.x * 256 + threadIdx.x;
  if (e >= E_TOT) return;
  int d = dst[e];
  int p = atomicAdd(&cursor[d], 1);
  col[row_start[d] + p] = src[e];
}

// ---------- tiled GEMM: out[n,COUT] = fix(in[n,CIN]) @ w  (+fused BN stats) ----
// stats are striped NSTRIPE ways by blockIdx to avoid same-address atomic serialization
template<int CIN, int COUT, bool FIX, bool STATS>
__global__ __launch_bounds__(256) void gemm_tile(
    const float* __restrict__ in, const float* __restrict__ w,
    float* __restrict__ out, float* __restrict__ stat, int n){
  constexpr int R = 8;
  constexpr int CPL = (COUT + 63) / 64;
  __shared__ float lds[4][R * CIN];
  __shared__ float sred[STATS ? 8 * COUT : 1];
  int wave = threadIdx.x >> 6, lane = threadIdx.x & 63;
  int base = (blockIdx.x * 4 + wave) * R;

  if (base < n){
    const float4* src4 = (const float4*)(in + (size_t)base * CIN);
    float4* dst4 = (float4*)lds[wave];
    int n4 = min(R, n - base) * CIN / 4;
    for (int i = lane; i < R * CIN / 4; i += 64){
      float4 v = (i < n4) ? src4[i] : make_float4(0.f, 0.f, 0.f, 0.f);
      if (FIX){
        v.x = isfinite(v.x) ? v.x : 0.f; v.y = isfinite(v.y) ? v.y : 0.f;
        v.z = isfinite(v.z) ? v.z : 0.f; v.w = isfinite(v.w) ? v.w : 0.f;
      }
      dst4[i] = v;
    }
  }
  __syncthreads();

  bool act = (COUT >= 64) || (lane < COUT);
  float acc[CPL][R];
  #pragma unroll
  for (int j = 0; j < CPL; j++)
    #pragma unroll
    for (int r = 0; r < R; r++) acc[j][r] = 0.f;

  if (base < n && act){
    const float4* l4 = (const float4*)lds[wave];
    for (int k = 0; k < CIN; k += 4){
      float4 wv[CPL];
      #pragma unroll
      for (int j = 0; j < CPL; j++){
        int c = lane + 64 * j;
        wv[j].x = w[(k + 0) * COUT + c];
        wv[j].y = w[(k + 1) * COUT + c];
        wv[j].z = w[(k + 2) * COUT + c];
        wv[j].w = w[(k + 3) * COUT + c];
      }
      #pragma unroll
      for (int r = 0; r < R; r++){
        float4 a = l4[(r * CIN + k) >> 2];
        #pragma unroll
        for (int j = 0; j < CPL; j++)
          acc[j][r] = fmaf(a.x, wv[j].x, fmaf(a.y, wv[j].y,
                      fmaf(a.z, wv[j].z, fmaf(a.w, wv[j].w, acc[j][r]))));
      }
    }
    int nrows = min(R, n - base);
    for (int r = 0; r < nrows; r++){
      #pragma unroll
      for (int j = 0; j < CPL; j++)
        out[(size_t)(base + r) * COUT + lane + 64 * j] = acc[j][r];
    }
  }

  if (STATS){
    #pragma unroll
    for (int j = 0; j < CPL; j++){
      float s = 0.f, q = 0.f;
      #pragma unroll
      for (int r = 0; r < R; r++){ s += acc[j][r]; q += acc[j][r] * acc[j][r]; }
      if (act){
        int c = lane + 64 * j;
        sred[(2 * wave + 0) * COUT + c] = s;
        sred[(2 * wave + 1) * COUT + c] = q;
      }
    }
    __syncthreads();
    int c = threadIdx.x;
    if (c < COUT){
      float S = 0.f, Q = 0.f;
      #pragma unroll
      for (int wv = 0; wv < 4; wv++){
        S += sred[(2 * wv + 0) * COUT + c];
        Q += sred[(2 * wv + 1) * COUT + c];
      }
      float* st = stat + (size_t)(blockIdx.x & (NSTRIPE - 1)) * 256;
      atomicAdd(&st[c], S);
      atomicAdd(&st[128 + c], Q);
    }
  }
}

// ---------- layer-1 node transform: u[n,16] = x[n] * wl[0,:] ----------
__global__ void node1_kernel(const float* __restrict__ x, const float* __restrict__ wl,
                             float* __restrict__ u){
  int i = blockIdx.x * 256 + threadIdx.x;
  if (i >= N_NODES * 16) return;
  u[i] = x[i >> 4] * wl[i & 15];
}

// ---------- generic node matmul (coarse layers only, n=512) ----------
__global__ void node_matmul(const float* __restrict__ in, int sin, int cin,
                            const float* __restrict__ wl, int coutShift,
                            float* __restrict__ u, int n){
  int cout = 1 << coutShift;
  long long idx = (long long)blockIdx.x * 256 + threadIdx.x;
  if (idx >= (long long)n * cout) return;
  int node = (int)(idx >> coutShift);
  int c = (int)idx & (cout - 1);
  const float* row = in + (long long)node * sin;
  float acc = 0.f;
  for (int k = 0; k < cin; ++k) acc = fmaf(row[k], wl[k * cout + c], acc);
  u[idx] = acc;
}

// ---------- CSR pull edge aggregation (XCD-swizzled, 64 channels/pass) ------
template<int CH>
__global__ __launch_bounds__(256) void edge_agg(
    const float* __restrict__ u, int ustride, int coff,
    const float* __restrict__ pos,
    const float* __restrict__ w3,   // = wl + cin*cout : rows (3, cout)
    int cout,
    const int* __restrict__ row_start, const int* __restrict__ col,
    float* __restrict__ agg){
  int wave = threadIdx.x >> 6, lane = threadIdx.x & 63;
  int g = blockIdx.x & 7;
  int d = g * NPG + (blockIdx.x >> 3) * 4 + wave;   // NPG/4 divides evenly
  bool act = (CH >= 64) || (lane < CH);
  int c = coff + (act ? lane : 0);
  float w0 = w3[c], w1 = w3[cout + c], w2 = w3[2 * cout + c];
  float px = pos[d * 3 + 0], py = pos[d * 3 + 1], pz = pos[d * 3 + 2];
  int e0 = row_start[d], e1 = row_start[d + 1];
  float acc0 = -INFINITY, acc1 = -INFINITY;
  for (int eb = e0; eb < e1; eb += 64){
    int m = min(64, e1 - eb);
    int sv = col[eb + min(lane, m - 1)];   // lane-parallel index preload
    for (int j = 0; j < m; j += 2){
      int sa = __shfl(sv, j, 64);
      int sb = __shfl(sv, min(j + 1, m - 1), 64);  // dup tail: idempotent for max
      float ax = pos[sa * 3 + 0] - px, ay = pos[sa * 3 + 1] - py, az = pos[sa * 3 + 2] - pz;
      float bx = pos[sb * 3 + 0] - px, by = pos[sb * 3 + 1] - py, bz = pos[sb * 3 + 2] - pz;
      float va = u[(size_t)sa * ustride + coff + lane];
      float vb = u[(size_t)sb * ustride + coff + lane];
      acc0 = fmaxf(acc0, fmaf(ax, w0, fmaf(ay, w1, fmaf(az, w2, va))));
      acc1 = fmaxf(acc1, fmaf(bx, w0, fmaf(by, w1, fmaf(bz, w2, vb))));
    }
  }
  if (act) agg[(size_t)d * cout + coff + lane] = fmaxf(acc0, acc1);
}

// ---------- BN statistics (coarse layers only; writes stripe 0) ----------
__global__ void stats_kernel(const float* __restrict__ y, int cout, int n,
                             float* __restrict__ stats){
  int c = threadIdx.x;
  if (c >= cout) return;
  int r0 = blockIdx.x * 512;
  int r1 = min(r0 + 512, n);
  float s = 0.f, q = 0.f;
  for (int r = r0; r < r1; ++r){
    float v = y[(long long)r * cout + c];
    s += v; q += v * v;
  }
  atomicAdd(&stats[c], s);
  atomicAdd(&stats[128 + c], q);
}

// sums NSTRIPE stripes of (256) stats, then computes scale/shift
__global__ void bn_finalize(const float* __restrict__ stats, const float* __restrict__ g,
                            const float* __restrict__ b, int cout, float invn,
                            float* __restrict__ ss){
  int c = threadIdx.x;
  if (c >= cout) return;
  float S = 0.f, Q = 0.f;
  for (int s = 0; s < NSTRIPE; s++){
    S += stats[s * 256 + c];
    Q += stats[s * 256 + 128 + c];
  }
  float mean = S * invn;
  float var = fmaxf(Q * invn - mean * mean, 0.f);
  float sc = g[c] * rsqrtf(var + 1e-5f);
  ss[c] = sc;
  ss[128 + c] = b[c] - mean * sc;
}

__global__ void bn_elu_apply4(const float4* __restrict__ y, const float* __restrict__ ss,
                              const float4* __restrict__ resid, float4* __restrict__ dest,
                              int coutMask, long long total4){
  long long i = (long long)blockIdx.x * 256 + threadIdx.x;
  if (i >= total4) return;
  int c0 = (int)((i * 4) & coutMask);
  float4 v = y[i];
  v.x = fmaf(v.x, ss[c0 + 0], ss[128 + c0 + 0]);
  v.y = fmaf(v.y, ss[c0 + 1], ss[128 + c0 + 1]);
  v.z = fmaf(v.z, ss[c0 + 2], ss[128 + c0 + 2]);
  v.w = fmaf(v.w, ss[c0 + 3], ss[128 + c0 + 3]);
  v.x = v.x > 0.f ? v.x : expm1f(v.x);
  v.y = v.y > 0.f ? v.y : expm1f(v.y);
  v.z = v.z > 0.f ? v.z : expm1f(v.z);
  v.w = v.w > 0.f ? v.w : expm1f(v.w);
  if (resid){
    float4 r = resid[i];
    v.x += r.x; v.y += r.y; v.z += r.z; v.w += r.w;
  }
  dest[i] = v;
}

// ---------- pool5 ----------
__global__ void pool5_a(const float* __restrict__ pos, const int* __restrict__ batch,
                        int* __restrict__ clus, float* __restrict__ cnt,
                        float* __restrict__ psum){
  int i = blockIdx.x * 256 + threadIdx.x;
  if (i >= N_NODES) return;
  int cx = min(max((int)floorf(pos[i * 3 + 0] * 8.f), 0), 7);
  int cy = min(max((int)floorf(pos[i * 3 + 1] * 8.f), 0), 7);
  int cl = batch[i] * 64 + cx * 8 + cy;
  clus[i] = cl;
  atomicAdd(&cnt[cl], 1.f);
  atomicAdd(&psum[cl * 3 + 0], pos[i * 3 + 0]);
  atomicAdd(&psum[cl * 3 + 1], pos[i * 3 + 1]);
  atomicAdd(&psum[cl * 3 + 2], pos[i * 3 + 2]);
}

__global__ void pool5_b(const float* __restrict__ h, const int* __restrict__ clus,
                        unsigned* __restrict__ hce){
  long long idx = (long long)blockIdx.x * 256 + threadIdx.x;
  if (idx >= (long long)N_NODES * 128) return;
  int node = (int)(idx >> 7), c = (int)idx & 127;
  atomicMax(&hce[clus[node] * 128 + c], fenc(h[idx]));
}

__global__ void pool5_c(const unsigned* __restrict__ hce, const float* __restrict__ cnt,
                        const float* __restrict__ psum, float* __restrict__ hcf,
                        float* __restrict__ posc, int* __restrict__ pf){
  int d = blockIdx.x, c = threadIdx.x;
  float v = fdec(hce[d * 128 + c]);
  hcf[d * 128 + c] = isfinite(v) ? v : 0.f;
  if (c < 3) posc[d * 3 + c] = psum[d * 3 + c] / fmaxf(cnt[d], 1.f);
  if (c == 0) pf[d * 64 + (d & 63)] = 1;   // coarse self-loop
}

__global__ void pair_edges(const int* __restrict__ src, const int* __restrict__ dst,
                           const int* __restrict__ clus, int* __restrict__ pf){
  int e = blockIdx.x * 256 + threadIdx.x;
  if (e >= E_TOT) return;
  int cs = clus[src[e]], cd = clus[dst[e]];
  pf[cd * 64 + (cs & 63)] = 1;
}

// ---------- coarse conv: dedup'd pairs, fused agg@wg ----------
__global__ __launch_bounds__(128) void coarse_conv(
    const float* __restrict__ u2, const float* __restrict__ posc,
    const float* __restrict__ wl, const int* __restrict__ pf,
    const float* __restrict__ wg, float* __restrict__ y2){
  __shared__ float sagg[128];
  int d = blockIdx.x, c = threadIdx.x;
  int g = d >> 6;
  float px = posc[d * 3 + 0], py = posc[d * 3 + 1], pz = posc[d * 3 + 2];
  const float* wb = wl + 128 * 128;  // rows 128..130 of (131,128)
  float w0 = wb[c], w1 = wb[128 + c], w2 = wb[256 + c];
  float acc = -INFINITY;
  for (int j = 0; j < 64; ++j){
    if (pf[d * 64 + j]){
      int s = g * 64 + j;
      float dx = posc[s * 3 + 0] - px;
      float dy = posc[s * 3 + 1] - py;
      float dz = posc[s * 3 + 2] - pz;
      float h = fmaf(dx, w0, fmaf(dy, w1, fmaf(dz, w2, u2[s * 128 + c])));
      acc = fmaxf(acc, h);
    }
  }
  sagg[c] = isfinite(acc) ? acc : 0.f;
  __syncthreads();
  float y = 0.f;
  for (int k = 0; k < 128; ++k) y = fmaf(sagg[k], wg[k * 128 + c], y);
  y2[d * 128 + c] = y;
}

// ---------- pool7 ----------
__global__ void pool7(const float* __restrict__ c7, const float* __restrict__ posc,
                      unsigned* __restrict__ xoe){
  int i = blockIdx.x, c = threadIdx.x;
  int g = i >> 6;
  int cx = min(max((int)floorf(posc[i * 3 + 0] * 4.f), 0), 3);
  int cy = min(max((int)floorf(posc[i * 3 + 1] * 4.f), 0), 3);
  int cl2 = g * 16 + cx * 4 + cy;
  atomicMax(&xoe[cl2 * 128 + c], fenc(c7[i * 128 + c]));
}

// ---------- final FC: (8,2048) @ (2048,10) ----------
__global__ void fc_kernel(const unsigned* __restrict__ xoe, const float* __restrict__ wfc,
                          float* __restrict__ out){
  int o = blockIdx.x;           // 0..79
  int b = o / 10, cls = o % 10;
  int lane = threadIdx.x;
  float s = 0.f;
  for (int k = lane; k < 2048; k += 64){
    float v = fdec(xoe[b * 2048 + k]);
    v = isfinite(v) ? v : 0.f;
    s = fmaf(v, wfc[k * 10 + cls], s);
  }
  for (int off = 32; off > 0; off >>= 1) s += __shfl_down(s, off, 64);
  if (lane == 0) out[o] = s;
}

// ---------- host ----------
extern "C" void kernel_launch(void* const* d_in, const int* in_sizes, int n_in,
                              void* d_out, int out_size, void* d_ws, size_t ws_size,
                              hipStream_t stream){
  (void)in_sizes; (void)n_in; (void)out_size; (void)ws_size;
  const float* X   = (const float*)d_in[0];
  const float* POS = (const float*)d_in[1];
  const int*   SRC = (const int*)d_in[2];
  const int*   DST = (const int*)d_in[3];
  const int*   BAT = (const int*)d_in[4];
  const float* WL[7]; const float* WG[7]; const float* GG[7]; const float* BB[7];
  for (int i = 0; i < 7; i++){
    WL[i] = (const float*)d_in[5 + 4 * i];
    WG[i] = (const float*)d_in[6 + 4 * i];
    GG[i] = (const float*)d_in[7 + 4 * i];
    BB[i] = (const float*)d_in[8 + 4 * i];
  }
  const float* WFC = (const float*)d_in[33];
  float* OUT = (float*)d_out;

  // workspace layout (floats)
  float* wsf = (float*)d_ws;
  size_t o = 0;
  auto alloc = [&](size_t nf){ float* p = wsf + o; o += nf; return p; };
  float* F0   = alloc((size_t)N_NODES * 128);
  float* F1   = alloc((size_t)N_NODES * 128);
  float* U    = alloc((size_t)N_NODES * 128);
  float* AG   = alloc((size_t)N_NODES * 128);
  float* HCF  = alloc(C1 * 128);
  float* POSC = alloc(2048);
  float* C6B  = alloc(C1 * 128);
  float* C7B  = alloc(C1 * 128);
  float* U2   = alloc(C1 * 128);
  float* Y2   = alloc(C1 * 128);
  float* SS   = alloc(9 * 256);
  int* COL  = (int*)alloc(E_TOT);
  int* ROWS = (int*)alloc(N_NODES + 8);
  int* PART = (int*)alloc(256);
  int* CLUS = (int*)alloc(N_NODES);
  // ---- zero zone (everything below is zeroed at call start) ----
  int* ZZ = (int*)(wsf + o);
  int*      DEG  = (int*)alloc(N_NODES);
  int*      CUR  = (int*)alloc(N_NODES);
  float*    STAT = alloc((size_t)9 * NSTRIPE * 256);
  unsigned* HCE  = (unsigned*)alloc(C1 * 128);
  float*    CNT  = alloc(512);
  float*    PSUM = alloc(2048);
  int*      PF   = (int*)alloc(C1 * 64);
  unsigned* XOE  = (unsigned*)alloc(128 * 128);
  int zz_n = (int)((int*)(wsf + o) - ZZ);

  zero_kernel<<<cdiv(zz_n, 256), 256, 0, stream>>>(ZZ, zz_n);

  // CSR build
  count_deg<<<cdiv(E_TOT, 256), 256, 0, stream>>>(DST, DEG);
  scan1<<<NB_SCAN, 256, 0, stream>>>(DEG, ROWS, PART);
  scan2<<<1, 1, 0, stream>>>(PART);
  scan3<<<cdiv(N_NODES, 256), 256, 0, stream>>>(ROWS, PART);
  fill_csr<<<cdiv(E_TOT, 256), 256, 0, stream>>>(SRC, DST, ROWS, CUR, COL);

  dim3 gE(8 * (NPG / 4)), bE(256);   // 25000 blocks, blockIdx&7 = graph/XCD
  dim3 gT(cdiv(N_NODES, 32)), bT(256);

  const size_t LSTAT = (size_t)NSTRIPE * 256;

  auto bn_tail = [&](int li, int cout, const float* resid, float* dest){
    bn_finalize<<<1, 128, 0, stream>>>(STAT + li * LSTAT, GG[li], BB[li], cout, 1.f / N_NODES, SS + li * 256);
    bn_elu_apply4<<<cdiv(N_NODES * cout / 4, 256), 256, 0, stream>>>(
        (const float4*)AG, SS + li * 256, (const float4*)resid, (float4*)dest,
        cout - 1, (long long)N_NODES * cout / 4);
  };

  // ---- layer 1: 1 -> 16 ----
  node1_kernel<<<cdiv(N_NODES * 16, 256), 256, 0, stream>>>(X, WL[0], U);
  edge_agg<16><<<gE, bE, 0, stream>>>(U, 16, 0, POS, WL[0] + 1 * 16, 16, ROWS, COL, AG);
  gemm_tile<16, 16, true, true><<<gT, bT, 0, stream>>>(AG, WG[0], AG, STAT + 0 * LSTAT, N_NODES);
  bn_tail(0, 16, nullptr, F0);

  // ---- layer 2: 16 -> 64 ----
  gemm_tile<16, 64, false, false><<<gT, bT, 0, stream>>>(F0, WL[1], U, nullptr, N_NODES);
  edge_agg<64><<<gE, bE, 0, stream>>>(U, 64, 0, POS, WL[1] + 16 * 64, 64, ROWS, COL, AG);
  gemm_tile<64, 64, true, true><<<gT, bT, 0, stream>>>(AG, WG[1], AG, STAT + 1 * LSTAT, N_NODES);
  bn_tail(1, 64, nullptr, F1);

  // ---- layer 3: 64 -> 64 ----
  gemm_tile<64, 64, false, false><<<gT, bT, 0, stream>>>(F1, WL[2], U, nullptr, N_NODES);
  edge_agg<64><<<gE, bE, 0, stream>>>(U, 64, 0, POS, WL[2] + 64 * 64, 64, ROWS, COL, AG);
  gemm_tile<64, 64, true, true><<<gT, bT, 0, stream>>>(AG, WG[2], AG, STAT + 2 * LSTAT, N_NODES);
  bn_tail(2, 64, nullptr, F0);

  // ---- layer 4: 64 -> 64 (+ residual = layer-2 output F1) ----
  gemm_tile<64, 64, false, false><<<gT, bT, 0, stream>>>(F0, WL[3], U, nullptr, N_NODES);
  edge_agg<64><<<gE, bE, 0, stream>>>(U, 64, 0, POS, WL[3] + 64 * 64, 64, ROWS, COL, AG);
  gemm_tile<64, 64, true, true><<<gT, bT, 0, stream>>>(AG, WG[3], AG, STAT + 3 * LSTAT, N_NODES);
  bn_tail(3, 64, F1, F1);

  // ---- layer 5: 64 -> 128 (two 64-channel passes so u-slice fits per-XCD L2) ----
  gemm_tile<64, 128, false, false><<<gT, bT, 0, stream>>>(F1, WL[4], U, nullptr, N_NODES);
  edge_agg<64><<<gE, bE, 0, stream>>>(U, 128, 0,  POS, WL[4] + 64 * 128, 128, ROWS, COL, AG);
  edge_agg<64><<<gE, bE, 0, stream>>>(U, 128, 64, POS, WL[4] + 64 * 128, 128, ROWS, COL, AG);
  gemm_tile<128, 128, true, true><<<gT, bT, 0, stream>>>(AG, WG[4], AG, STAT + 4 * LSTAT, N_NODES);
  bn_tail(4, 128, nullptr, F0);

  // pool5
  pool5_a<<<cdiv(N_NODES, 256), 256, 0, stream>>>(POS, BAT, CLUS, CNT, PSUM);
  pool5_b<<<cdiv(N_NODES * 128, 256), 256, 0, stream>>>(F0, CLUS, HCE);
  pool5_c<<<C1, 128, 0, stream>>>(HCE, CNT, PSUM, HCF, POSC, PF);
  pair_edges<<<cdiv(E_TOT, 256), 256, 0, stream>>>(SRC, DST, CLUS, PF);

  auto coarse_layer = [&](const float* in, int li, const float* resid, float* dest){
    node_matmul<<<cdiv(C1 * 128, 256), 256, 0, stream>>>(in, 128, 128, WL[li], 7, U2, C1);
    coarse_conv<<<C1, 128, 0, stream>>>(U2, POSC, WL[li], PF, WG[li], Y2);
    stats_kernel<<<1, 128, 0, stream>>>(Y2, 128, C1, STAT + li * LSTAT);
    bn_finalize<<<1, 128, 0, stream>>>(STAT + li * LSTAT, GG[li], BB[li], 128, 1.f / C1, SS + li * 256);
    bn_elu_apply4<<<cdiv(C1 * 128 / 4, 256), 256, 0, stream>>>(
        (const float4*)Y2, SS + li * 256, (const float4*)resid, (float4*)dest,
        127, (long long)C1 * 128 / 4);
  };

  coarse_layer(HCF, 5, nullptr, C6B);
  coarse_layer(C6B, 6, HCF,    C7B);   // + residual (sc2 = hc)

  pool7<<<C1, 128, 0, stream>>>(C7B, POSC, XOE);
  fc_kernel<<<80, 64, 0, stream>>>(XOE, WFC, OUT);
}

// Round 5
// 1252.862 us; speedup vs baseline: 2.3785x; 1.2543x over previous
//
#include <hip/hip_runtime.h>
#include <math.h>

#define N_NODES 100000
#define NPG     12500
#define E_TOT   1700000
#define C1      512
#define NB_SCAN 98   // ceil(100000/1024)
#define NSTRIPE 64   // stats striping: contention 3125 -> ~49 per address

static inline int cdiv(int a, int b){ return (a + b - 1) / b; }

// ---------- ordered-float encoding for atomic max ----------
__device__ __forceinline__ unsigned fenc(float f){
  unsigned u = __float_as_uint(f);
  return (u >> 31) ? ~u : (u | 0x80000000u);
}
__device__ __forceinline__ float fdec(unsigned e){
  return (e & 0x80000000u) ? __uint_as_float(e ^ 0x80000000u) : __uint_as_float(~e);
}
// note: fdec(0) = NaN  -> "empty segment" -> replaced by 0 like the reference

// ---------- utility ----------
__global__ void zero_kernel(int* __restrict__ p, int n){
  int i = blockIdx.x * 256 + threadIdx.x;
  if (i < n) p[i] = 0;
}

// ---------- CSR build (dst-indexed), reused by all 5 fine layers ----------
__global__ void count_deg(const int* __restrict__ dst, int* __restrict__ deg){
  int e = blockIdx.x * 256 + threadIdx.x;
  if (e < E_TOT) atomicAdd(&deg[dst[e]], 1);
}

__global__ void scan1(const int* __restrict__ deg, int* __restrict__ row_start,
                      int* __restrict__ partials){
  __shared__ int sm[256];
  int t = threadIdx.x, b = blockIdx.x;
  int base = b * 1024 + t * 4;
  int d0 = (base + 0 < N_NODES) ? deg[base + 0] : 0;
  int d1 = (base + 1 < N_NODES) ? deg[base + 1] : 0;
  int d2 = (base + 2 < N_NODES) ? deg[base + 2] : 0;
  int d3 = (base + 3 < N_NODES) ? deg[base + 3] : 0;
  int s = d0 + d1 + d2 + d3;
  sm[t] = s; __syncthreads();
  for (int off = 1; off < 256; off <<= 1){
    int v = (t >= off) ? sm[t - off] : 0;
    __syncthreads();
    sm[t] += v;
    __syncthreads();
  }
  int excl = sm[t] - s;
  if (base + 0 < N_NODES) row_start[base + 0] = excl;
  if (base + 1 < N_NODES) row_start[base + 1] = excl + d0;
  if (base + 2 < N_NODES) row_start[base + 2] = excl + d0 + d1;
  if (base + 3 < N_NODES) row_start[base + 3] = excl + d0 + d1 + d2;
  if (t == 255) partials[b] = sm[255];
}

__global__ void scan2(int* __restrict__ partials){
  if (threadIdx.x == 0 && blockIdx.x == 0){
    int acc = 0;
    for (int i = 0; i < NB_SCAN; i++){ int v = partials[i]; partials[i] = acc; acc += v; }
  }
}

__global__ void scan3(int* __restrict__ row_start, const int* __restrict__ partials){
  int i = blockIdx.x * 256 + threadIdx.x;
  if (i < N_NODES) row_start[i] += partials[i >> 10];
  if (i == 0) row_start[N_NODES] = E_TOT;
}

__global__ void fill_csr(const int* __restrict__ src, const int* __restrict__ dst,
                         const int* __restrict__ row_start, int* __restrict__ cursor,
                         int* __restrict__ col){
  int e = blockIdx.x * 256 + threadIdx.x;
  if (e >= E_TOT) return;
  int d = dst[e];
  int p = atomicAdd(&cursor[d], 1);
  col[row_start[d] + p] = src[e];
}

// ---------- tiled GEMM: out[n,COUT] = fix(in[n,CIN]) @ w  (+fused BN stats) ----
// stats are striped NSTRIPE ways by blockIdx to avoid same-address atomic serialization
template<int CIN, int COUT, bool FIX, bool STATS>
__global__ __launch_bounds__(256) void gemm_tile(
    const float* __restrict__ in, const float* __restrict__ w,
    float* __restrict__ out, float* __restrict__ stat, int n){
  constexpr int R = 8;
  constexpr int CPL = (COUT + 63) / 64;
  __shared__ float lds[4][R * CIN];
  __shared__ float sred[STATS ? 8 * COUT : 1];
  int wave = threadIdx.x >> 6, lane = threadIdx.x & 63;
  int base = (blockIdx.x * 4 + wave) * R;

  if (base < n){
    const float4* src4 = (const float4*)(in + (size_t)base * CIN);
    float4* dst4 = (float4*)lds[wave];
    int n4 = min(R, n - base) * CIN / 4;
    for (int i = lane; i < R * CIN / 4; i += 64){
      float4 v = (i < n4) ? src4[i] : make_float4(0.f, 0.f, 0.f, 0.f);
      if (FIX){
        v.x = isfinite(v.x) ? v.x : 0.f; v.y = isfinite(v.y) ? v.y : 0.f;
        v.z = isfinite(v.z) ? v.z : 0.f; v.w = isfinite(v.w) ? v.w : 0.f;
      }
      dst4[i] = v;
    }
  }
  __syncthreads();

  bool act = (COUT >= 64) || (lane < COUT);
  float acc[CPL][R];
  #pragma unroll
  for (int j = 0; j < CPL; j++)
    #pragma unroll
    for (int r = 0; r < R; r++) acc[j][r] = 0.f;

  if (base < n && act){
    const float4* l4 = (const float4*)lds[wave];
    for (int k = 0; k < CIN; k += 4){
      float4 wv[CPL];
      #pragma unroll
      for (int j = 0; j < CPL; j++){
        int c = lane + 64 * j;
        wv[j].x = w[(k + 0) * COUT + c];
        wv[j].y = w[(k + 1) * COUT + c];
        wv[j].z = w[(k + 2) * COUT + c];
        wv[j].w = w[(k + 3) * COUT + c];
      }
      #pragma unroll
      for (int r = 0; r < R; r++){
        float4 a = l4[(r * CIN + k) >> 2];
        #pragma unroll
        for (int j = 0; j < CPL; j++)
          acc[j][r] = fmaf(a.x, wv[j].x, fmaf(a.y, wv[j].y,
                      fmaf(a.z, wv[j].z, fmaf(a.w, wv[j].w, acc[j][r]))));
      }
    }
    int nrows = min(R, n - base);
    for (int r = 0; r < nrows; r++){
      #pragma unroll
      for (int j = 0; j < CPL; j++)
        out[(size_t)(base + r) * COUT + lane + 64 * j] = acc[j][r];
    }
  }

  if (STATS){
    #pragma unroll
    for (int j = 0; j < CPL; j++){
      float s = 0.f, q = 0.f;
      #pragma unroll
      for (int r = 0; r < R; r++){ s += acc[j][r]; q += acc[j][r] * acc[j][r]; }
      if (act){
        int c = lane + 64 * j;
        sred[(2 * wave + 0) * COUT + c] = s;
        sred[(2 * wave + 1) * COUT + c] = q;
      }
    }
    __syncthreads();
    int c = threadIdx.x;
    if (c < COUT){
      float S = 0.f, Q = 0.f;
      #pragma unroll
      for (int wv = 0; wv < 4; wv++){
        S += sred[(2 * wv + 0) * COUT + c];
        Q += sred[(2 * wv + 1) * COUT + c];
      }
      float* st = stat + (size_t)(blockIdx.x & (NSTRIPE - 1)) * 256;
      atomicAdd(&st[c], S);
      atomicAdd(&st[128 + c], Q);
    }
  }
}

// ---------- layer-1 node transform: u[n,16] = x[n] * wl[0,:] ----------
__global__ void node1_kernel(const float* __restrict__ x, const float* __restrict__ wl,
                             float* __restrict__ u){
  int i = blockIdx.x * 256 + threadIdx.x;
  if (i >= N_NODES * 16) return;
  u[i] = x[i >> 4] * wl[i & 15];
}

// ---------- CSR pull edge aggregation (XCD-swizzled, 64 channels/pass) ------
template<int CH>
__global__ __launch_bounds__(256) void edge_agg(
    const float* __restrict__ u, int ustride, int coff,
    const float* __restrict__ pos,
    const float* __restrict__ w3,   // = wl + cin*cout : rows (3, cout)
    int cout,
    const int* __restrict__ row_start, const int* __restrict__ col,
    float* __restrict__ agg){
  int wave = threadIdx.x >> 6, lane = threadIdx.x & 63;
  int g = blockIdx.x & 7;
  int d = g * NPG + (blockIdx.x >> 3) * 4 + wave;   // NPG/4 divides evenly
  bool act = (CH >= 64) || (lane < CH);
  int c = coff + (act ? lane : 0);
  float w0 = w3[c], w1 = w3[cout + c], w2 = w3[2 * cout + c];
  float px = pos[d * 3 + 0], py = pos[d * 3 + 1], pz = pos[d * 3 + 2];
  int e0 = row_start[d], e1 = row_start[d + 1];
  float acc0 = -INFINITY, acc1 = -INFINITY;
  for (int eb = e0; eb < e1; eb += 64){
    int m = min(64, e1 - eb);
    int sv = col[eb + min(lane, m - 1)];   // lane-parallel index preload
    for (int j = 0; j < m; j += 2){
      int sa = __shfl(sv, j, 64);
      int sb = __shfl(sv, min(j + 1, m - 1), 64);  // dup tail: idempotent for max
      float ax = pos[sa * 3 + 0] - px, ay = pos[sa * 3 + 1] - py, az = pos[sa * 3 + 2] - pz;
      float bx = pos[sb * 3 + 0] - px, by = pos[sb * 3 + 1] - py, bz = pos[sb * 3 + 2] - pz;
      float va = u[(size_t)sa * ustride + coff + lane];
      float vb = u[(size_t)sb * ustride + coff + lane];
      acc0 = fmaxf(acc0, fmaf(ax, w0, fmaf(ay, w1, fmaf(az, w2, va))));
      acc1 = fmaxf(acc1, fmaf(bx, w0, fmaf(by, w1, fmaf(bz, w2, vb))));
    }
  }
  if (act) agg[(size_t)d * cout + coff + lane] = fmaxf(acc0, acc1);
}

// sums NSTRIPE stripes of (256) stats, then computes scale/shift
__global__ void bn_finalize(const float* __restrict__ stats, const float* __restrict__ g,
                            const float* __restrict__ b, int cout, float invn,
                            float* __restrict__ ss){
  int c = threadIdx.x;
  if (c >= cout) return;
  float S = 0.f, Q = 0.f;
  for (int s = 0; s < NSTRIPE; s++){
    S += stats[s * 256 + c];
    Q += stats[s * 256 + 128 + c];
  }
  float mean = S * invn;
  float var = fmaxf(Q * invn - mean * mean, 0.f);
  float sc = g[c] * rsqrtf(var + 1e-5f);
  ss[c] = sc;
  ss[128 + c] = b[c] - mean * sc;
}

__global__ void bn_elu_apply4(const float4* __restrict__ y, const float* __restrict__ ss,
                              const float4* __restrict__ resid, float4* __restrict__ dest,
                              int coutMask, long long total4){
  long long i = (long long)blockIdx.x * 256 + threadIdx.x;
  if (i >= total4) return;
  int c0 = (int)((i * 4) & coutMask);
  float4 v = y[i];
  v.x = fmaf(v.x, ss[c0 + 0], ss[128 + c0 + 0]);
  v.y = fmaf(v.y, ss[c0 + 1], ss[128 + c0 + 1]);
  v.z = fmaf(v.z, ss[c0 + 2], ss[128 + c0 + 2]);
  v.w = fmaf(v.w, ss[c0 + 3], ss[128 + c0 + 3]);
  v.x = v.x > 0.f ? v.x : expm1f(v.x);
  v.y = v.y > 0.f ? v.y : expm1f(v.y);
  v.z = v.z > 0.f ? v.z : expm1f(v.z);
  v.w = v.w > 0.f ? v.w : expm1f(v.w);
  if (resid){
    float4 r = resid[i];
    v.x += r.x; v.y += r.y; v.z += r.z; v.w += r.w;
  }
  dest[i] = v;
}

// ---------- pool5 ----------
__global__ void pool5_a(const float* __restrict__ pos, const int* __restrict__ batch,
                        int* __restrict__ clus, float* __restrict__ cnt,
                        float* __restrict__ psum){
  int i = blockIdx.x * 256 + threadIdx.x;
  if (i >= N_NODES) return;
  int cx = min(max((int)floorf(pos[i * 3 + 0] * 8.f), 0), 7);
  int cy = min(max((int)floorf(pos[i * 3 + 1] * 8.f), 0), 7);
  int cl = batch[i] * 64 + cx * 8 + cy;
  clus[i] = cl;
  atomicAdd(&cnt[cl], 1.f);
  atomicAdd(&psum[cl * 3 + 0], pos[i * 3 + 0]);
  atomicAdd(&psum[cl * 3 + 1], pos[i * 3 + 1]);
  atomicAdd(&psum[cl * 3 + 2], pos[i * 3 + 2]);
}

__global__ void pool5_b(const float* __restrict__ h, const int* __restrict__ clus,
                        unsigned* __restrict__ hce){
  long long idx = (long long)blockIdx.x * 256 + threadIdx.x;
  if (idx >= (long long)N_NODES * 128) return;
  int node = (int)(idx >> 7), c = (int)idx & 127;
  atomicMax(&hce[clus[node] * 128 + c], fenc(h[idx]));
}

__global__ void pool5_c(const unsigned* __restrict__ hce, const float* __restrict__ cnt,
                        const float* __restrict__ psum, float* __restrict__ hcf,
                        float* __restrict__ posc, int* __restrict__ pf){
  int d = blockIdx.x, c = threadIdx.x;
  float v = fdec(hce[d * 128 + c]);
  hcf[d * 128 + c] = isfinite(v) ? v : 0.f;
  if (c < 3) posc[d * 3 + c] = psum[d * 3 + c] / fmaxf(cnt[d], 1.f);
  if (c == 0) pf[d * 64 + (d & 63)] = 1;   // coarse self-loop
}

__global__ void pair_edges(const int* __restrict__ src, const int* __restrict__ dst,
                           const int* __restrict__ clus, int* __restrict__ pf){
  int e = blockIdx.x * 256 + threadIdx.x;
  if (e >= E_TOT) return;
  int cs = clus[src[e]], cd = clus[dst[e]];
  pf[cd * 64 + (cs & 63)] = 1;
}

// ---------- coarse conv: dedup'd pairs, fused agg@wg + fused BN stats ----------
__global__ __launch_bounds__(128) void coarse_conv(
    const float* __restrict__ u2, const float* __restrict__ posc,
    const float* __restrict__ wl, const int* __restrict__ pf,
    const float* __restrict__ wg, float* __restrict__ y2,
    float* __restrict__ stat){
  __shared__ float sagg[128];
  int d = blockIdx.x, c = threadIdx.x;
  int g = d >> 6;
  float px = posc[d * 3 + 0], py = posc[d * 3 + 1], pz = posc[d * 3 + 2];
  const float* wb = wl + 128 * 128;  // rows 128..130 of (131,128)
  float w0 = wb[c], w1 = wb[128 + c], w2 = wb[256 + c];
  float acc = -INFINITY;
  for (int j = 0; j < 64; ++j){
    if (pf[d * 64 + j]){
      int s = g * 64 + j;
      float dx = posc[s * 3 + 0] - px;
      float dy = posc[s * 3 + 1] - py;
      float dz = posc[s * 3 + 2] - pz;
      float h = fmaf(dx, w0, fmaf(dy, w1, fmaf(dz, w2, u2[s * 128 + c])));
      acc = fmaxf(acc, h);
    }
  }
  sagg[c] = isfinite(acc) ? acc : 0.f;
  __syncthreads();
  float y = 0.f;
  for (int k = 0; k < 128; ++k) y = fmaf(sagg[k], wg[k * 128 + c], y);
  y2[d * 128 + c] = y;
  // fused BN stats: 512 blocks striped 64 ways -> 8 serialized adds/address
  float* st = stat + (size_t)(d & (NSTRIPE - 1)) * 256;
  atomicAdd(&st[c], y);
  atomicAdd(&st[128 + c], y * y);
}

// ---------- pool7 ----------
__global__ void pool7(const float* __restrict__ c7, const float* __restrict__ posc,
                      unsigned* __restrict__ xoe){
  int i = blockIdx.x, c = threadIdx.x;
  int g = i >> 6;
  int cx = min(max((int)floorf(posc[i * 3 + 0] * 4.f), 0), 3);
  int cy = min(max((int)floorf(posc[i * 3 + 1] * 4.f), 0), 3);
  int cl2 = g * 16 + cx * 4 + cy;
  atomicMax(&xoe[cl2 * 128 + c], fenc(c7[i * 128 + c]));
}

// ---------- final FC: (8,2048) @ (2048,10) ----------
__global__ void fc_kernel(const unsigned* __restrict__ xoe, const float* __restrict__ wfc,
                          float* __restrict__ out){
  int o = blockIdx.x;           // 0..79
  int b = o / 10, cls = o % 10;
  int lane = threadIdx.x;
  float s = 0.f;
  for (int k = lane; k < 2048; k += 64){
    float v = fdec(xoe[b * 2048 + k]);
    v = isfinite(v) ? v : 0.f;
    s = fmaf(v, wfc[k * 10 + cls], s);
  }
  for (int off = 32; off > 0; off >>= 1) s += __shfl_down(s, off, 64);
  if (lane == 0) out[o] = s;
}

// ---------- host ----------
extern "C" void kernel_launch(void* const* d_in, const int* in_sizes, int n_in,
                              void* d_out, int out_size, void* d_ws, size_t ws_size,
                              hipStream_t stream){
  (void)in_sizes; (void)n_in; (void)out_size; (void)ws_size;
  const float* X   = (const float*)d_in[0];
  const float* POS = (const float*)d_in[1];
  const int*   SRC = (const int*)d_in[2];
  const int*   DST = (const int*)d_in[3];
  const int*   BAT = (const int*)d_in[4];
  const float* WL[7]; const float* WG[7]; const float* GG[7]; const float* BB[7];
  for (int i = 0; i < 7; i++){
    WL[i] = (const float*)d_in[5 + 4 * i];
    WG[i] = (const float*)d_in[6 + 4 * i];
    GG[i] = (const float*)d_in[7 + 4 * i];
    BB[i] = (const float*)d_in[8 + 4 * i];
  }
  const float* WFC = (const float*)d_in[33];
  float* OUT = (float*)d_out;

  // workspace layout (floats)
  float* wsf = (float*)d_ws;
  size_t o = 0;
  auto alloc = [&](size_t nf){ float* p = wsf + o; o += nf; return p; };
  float* F0   = alloc((size_t)N_NODES * 128);
  float* F1   = alloc((size_t)N_NODES * 128);
  float* U    = alloc((size_t)N_NODES * 128);
  float* AG   = alloc((size_t)N_NODES * 128);
  float* HCF  = alloc(C1 * 128);
  float* POSC = alloc(2048);
  float* C6B  = alloc(C1 * 128);
  float* C7B  = alloc(C1 * 128);
  float* U2   = alloc(C1 * 128);
  float* Y2   = alloc(C1 * 128);
  float* SS   = alloc(9 * 256);
  int* COL  = (int*)alloc(E_TOT);
  int* ROWS = (int*)alloc(N_NODES + 8);
  int* PART = (int*)alloc(256);
  int* CLUS = (int*)alloc(N_NODES);
  // ---- zero zone (everything below is zeroed at call start) ----
  int* ZZ = (int*)(wsf + o);
  int*      DEG  = (int*)alloc(N_NODES);
  int*      CUR  = (int*)alloc(N_NODES);
  float*    STAT = alloc((size_t)9 * NSTRIPE * 256);
  unsigned* HCE  = (unsigned*)alloc(C1 * 128);
  float*    CNT  = alloc(512);
  float*    PSUM = alloc(2048);
  int*      PF   = (int*)alloc(C1 * 64);
  unsigned* XOE  = (unsigned*)alloc(128 * 128);
  int zz_n = (int)((int*)(wsf + o) - ZZ);

  zero_kernel<<<cdiv(zz_n, 256), 256, 0, stream>>>(ZZ, zz_n);

  // CSR build
  count_deg<<<cdiv(E_TOT, 256), 256, 0, stream>>>(DST, DEG);
  scan1<<<NB_SCAN, 256, 0, stream>>>(DEG, ROWS, PART);
  scan2<<<1, 1, 0, stream>>>(PART);
  scan3<<<cdiv(N_NODES, 256), 256, 0, stream>>>(ROWS, PART);
  fill_csr<<<cdiv(E_TOT, 256), 256, 0, stream>>>(SRC, DST, ROWS, CUR, COL);

  dim3 gE(8 * (NPG / 4)), bE(256);   // 25000 blocks, blockIdx&7 = graph/XCD
  dim3 gT(cdiv(N_NODES, 32)), bT(256);

  const size_t LSTAT = (size_t)NSTRIPE * 256;

  auto bn_tail = [&](int li, int cout, const float* resid, float* dest){
    bn_finalize<<<1, 128, 0, stream>>>(STAT + li * LSTAT, GG[li], BB[li], cout, 1.f / N_NODES, SS + li * 256);
    bn_elu_apply4<<<cdiv(N_NODES * cout / 4, 256), 256, 0, stream>>>(
        (const float4*)AG, SS + li * 256, (const float4*)resid, (float4*)dest,
        cout - 1, (long long)N_NODES * cout / 4);
  };

  // ---- layer 1: 1 -> 16 ----
  node1_kernel<<<cdiv(N_NODES * 16, 256), 256, 0, stream>>>(X, WL[0], U);
  edge_agg<16><<<gE, bE, 0, stream>>>(U, 16, 0, POS, WL[0] + 1 * 16, 16, ROWS, COL, AG);
  gemm_tile<16, 16, true, true><<<gT, bT, 0, stream>>>(AG, WG[0], AG, STAT + 0 * LSTAT, N_NODES);
  bn_tail(0, 16, nullptr, F0);

  // ---- layer 2: 16 -> 64 ----
  gemm_tile<16, 64, false, false><<<gT, bT, 0, stream>>>(F0, WL[1], U, nullptr, N_NODES);
  edge_agg<64><<<gE, bE, 0, stream>>>(U, 64, 0, POS, WL[1] + 16 * 64, 64, ROWS, COL, AG);
  gemm_tile<64, 64, true, true><<<gT, bT, 0, stream>>>(AG, WG[1], AG, STAT + 1 * LSTAT, N_NODES);
  bn_tail(1, 64, nullptr, F1);

  // ---- layer 3: 64 -> 64 ----
  gemm_tile<64, 64, false, false><<<gT, bT, 0, stream>>>(F1, WL[2], U, nullptr, N_NODES);
  edge_agg<64><<<gE, bE, 0, stream>>>(U, 64, 0, POS, WL[2] + 64 * 64, 64, ROWS, COL, AG);
  gemm_tile<64, 64, true, true><<<gT, bT, 0, stream>>>(AG, WG[2], AG, STAT + 2 * LSTAT, N_NODES);
  bn_tail(2, 64, nullptr, F0);

  // ---- layer 4: 64 -> 64 (+ residual = layer-2 output F1) ----
  gemm_tile<64, 64, false, false><<<gT, bT, 0, stream>>>(F0, WL[3], U, nullptr, N_NODES);
  edge_agg<64><<<gE, bE, 0, stream>>>(U, 64, 0, POS, WL[3] + 64 * 64, 64, ROWS, COL, AG);
  gemm_tile<64, 64, true, true><<<gT, bT, 0, stream>>>(AG, WG[3], AG, STAT + 3 * LSTAT, N_NODES);
  bn_tail(3, 64, F1, F1);

  // ---- layer 5: 64 -> 128 (two 64-channel passes so u-slice fits per-XCD L2) ----
  gemm_tile<64, 128, false, false><<<gT, bT, 0, stream>>>(F1, WL[4], U, nullptr, N_NODES);
  edge_agg<64><<<gE, bE, 0, stream>>>(U, 128, 0,  POS, WL[4] + 64 * 128, 128, ROWS, COL, AG);
  edge_agg<64><<<gE, bE, 0, stream>>>(U, 128, 64, POS, WL[4] + 64 * 128, 128, ROWS, COL, AG);
  gemm_tile<128, 128, true, true><<<gT, bT, 0, stream>>>(AG, WG[4], AG, STAT + 4 * LSTAT, N_NODES);
  bn_tail(4, 128, nullptr, F0);

  // pool5
  pool5_a<<<cdiv(N_NODES, 256), 256, 0, stream>>>(POS, BAT, CLUS, CNT, PSUM);
  pool5_b<<<cdiv(N_NODES * 128, 256), 256, 0, stream>>>(F0, CLUS, HCE);
  pool5_c<<<C1, 128, 0, stream>>>(HCE, CNT, PSUM, HCF, POSC, PF);
  pair_edges<<<cdiv(E_TOT, 256), 256, 0, stream>>>(SRC, DST, CLUS, PF);

  auto coarse_layer = [&](const float* in, int li, const float* resid, float* dest){
    gemm_tile<128, 128, false, false><<<cdiv(C1, 32), bT, 0, stream>>>(in, WL[li], U2, nullptr, C1);
    coarse_conv<<<C1, 128, 0, stream>>>(U2, POSC, WL[li], PF, WG[li], Y2, STAT + li * LSTAT);
    bn_finalize<<<1, 128, 0, stream>>>(STAT + li * LSTAT, GG[li], BB[li], 128, 1.f / C1, SS + li * 256);
    bn_elu_apply4<<<cdiv(C1 * 128 / 4, 256), 256, 0, stream>>>(
        (const float4*)Y2, SS + li * 256, (const float4*)resid, (float4*)dest,
        127, (long long)C1 * 128 / 4);
  };

  coarse_layer(HCF, 5, nullptr, C6B);
  coarse_layer(C6B, 6, HCF,    C7B);   // + residual (sc2 = hc)

  pool7<<<C1, 128, 0, stream>>>(C7B, POSC, XOE);
  fc_kernel<<<80, 64, 0, stream>>>(XOE, WFC, OUT);
}